// Round 1
// baseline (574.779 us; speedup 1.0000x reference)
//
#include <hip/hip_runtime.h>

typedef unsigned short u16;
typedef __bf16 bf16x8 __attribute__((ext_vector_type(8)));
typedef float f32x4 __attribute__((ext_vector_type(4)));

#define DEV __device__ __forceinline__

constexpr int Bb = 4, Tt = 2048, Dd = 1024, Hh = 16, HDd = 64;
constexpr int MM = Bb * Tt;        // 8192
constexpr float QSCALE = 0.125f * 1.4426950408889634f;  // 1/sqrt(64) * log2(e)

DEV u16 f2bf(float f) {
  unsigned u = __float_as_uint(f);
  u += 0x7fffu + ((u >> 16) & 1u);   // RNE
  return (u16)(u >> 16);
}

DEV void gload_lds16(const u16* g, u16* l) {
  __builtin_amdgcn_global_load_lds(
      (const __attribute__((address_space(1))) void*)g,
      (__attribute__((address_space(3))) void*)l, 16, 0, 0);
}

// ---------------- cast x -> bf16 ----------------
__global__ __launch_bounds__(256) void cast_x_kernel(const float* __restrict__ in,
                                                     u16* __restrict__ out, int n8) {
  int i = blockIdx.x * 256 + threadIdx.x;
  if (i >= n8) return;
  const float4* p = (const float4*)in + (size_t)i * 2;
  float4 v0 = p[0], v1 = p[1];
  union { u16 u[8]; uint4 v; } t;
  t.u[0] = f2bf(v0.x); t.u[1] = f2bf(v0.y); t.u[2] = f2bf(v0.z); t.u[3] = f2bf(v0.w);
  t.u[4] = f2bf(v1.x); t.u[5] = f2bf(v1.y); t.u[6] = f2bf(v1.z); t.u[7] = f2bf(v1.w);
  ((uint4*)out)[i] = t.v;
}

// ---------- cast + transpose weights: [K][N] f32 -> [N][K] bf16 ----------
__global__ __launch_bounds__(256) void wcast_t_kernel(const float* __restrict__ in,
                                                      u16* __restrict__ out, int K, int N) {
  __shared__ float tile[32][33];
  int n0 = blockIdx.x * 32, k0 = blockIdx.y * 32;
  int tx = threadIdx.x & 31, ty = threadIdx.x >> 5;
  #pragma unroll
  for (int yy = ty; yy < 32; yy += 8)
    tile[yy][tx] = in[(size_t)(k0 + yy) * N + n0 + tx];
  __syncthreads();
  #pragma unroll
  for (int yy = ty; yy < 32; yy += 8)
    out[(size_t)(n0 + yy) * K + k0 + tx] = f2bf(tile[tx][yy]);
}

// ---------------- V [bh][t][d] -> Vt [bh][d][t] (bf16) ----------------
__global__ __launch_bounds__(256) void vtrans_kernel(const u16* __restrict__ V,
                                                     u16* __restrict__ Vt) {
  __shared__ u16 tile[32][33];
  size_t base = (size_t)blockIdx.z * Tt * HDd;
  int t0 = blockIdx.x * 32, d0 = blockIdx.y * 32;
  int tx = threadIdx.x & 31, ty = threadIdx.x >> 5;
  #pragma unroll
  for (int yy = ty; yy < 32; yy += 8)
    tile[yy][tx] = V[base + (size_t)(t0 + yy) * HDd + d0 + tx];
  __syncthreads();
  #pragma unroll
  for (int yy = ty; yy < 32; yy += 8)
    Vt[base + (size_t)(d0 + yy) * Tt + t0 + tx] = tile[tx][yy];
}

// ---------------- GEMM: A[M][K] bf16 * Bt[N][K] bf16 ----------------
// 128x128 tile, BK=32, 4 waves 2x2. global_load_lds width16, double-buffered.
// LDS slot-swizzle: 16B slot s at row r holds k-slot (s ^ ((r>>1)&3)).
DEV void stage_tile(const u16* __restrict__ src, int row0, int k0, int ld, u16* lds) {
  int t = threadIdx.x, w = t >> 6;
  #pragma unroll
  for (int j = 0; j < 2; ++j) {
    int e = (j * 256 + t) * 8;
    int r = e >> 5;
    int slot = (e >> 3) & 3;
    int c = (slot ^ ((r >> 1) & 3)) << 3;
    gload_lds16(src + (size_t)(row0 + r) * ld + k0 + c, lds + j * 2048 + w * 512);
  }
}

template <int EPI>   // 0: QKV scatter epilogue, 1: plain f32 + bias
__global__ __launch_bounds__(256) void gemm_bt_kernel(
    const u16* __restrict__ A, const u16* __restrict__ Bt,
    const float* __restrict__ bias, float* __restrict__ Cf,
    u16* __restrict__ Qb, u16* __restrict__ Kb, u16* __restrict__ Vb,
    int M, int N, int Kd) {
  __shared__ __align__(16) u16 As[2][4096];
  __shared__ __align__(16) u16 Bs[2][4096];
  int m0 = blockIdx.y * 128, n0 = blockIdx.x * 128;
  int tid = threadIdx.x, l = tid & 63, w = tid >> 6;
  int lo = l & 15, g = l >> 4;
  int wm = (w >> 1) * 64, wn = (w & 1) * 64;
  f32x4 acc[4][4] = {};
  stage_tile(A, m0, 0, Kd, As[0]);
  stage_tile(Bt, n0, 0, Kd, Bs[0]);
  __syncthreads();
  int nk = Kd >> 5;
  for (int kt = 0; kt < nk; ++kt) {
    int cur = kt & 1;
    if (kt + 1 < nk) {
      stage_tile(A, m0, (kt + 1) * 32, Kd, As[cur ^ 1]);
      stage_tile(Bt, n0, (kt + 1) * 32, Kd, Bs[cur ^ 1]);
    }
    bf16x8 a[4], b[4];
    #pragma unroll
    for (int i = 0; i < 4; ++i) {
      int row = wm + i * 16 + lo;
      a[i] = *(const bf16x8*)&As[cur][row * 32 + ((g ^ ((row >> 1) & 3)) << 3)];
    }
    #pragma unroll
    for (int j = 0; j < 4; ++j) {
      int row = wn + j * 16 + lo;
      b[j] = *(const bf16x8*)&Bs[cur][row * 32 + ((g ^ ((row >> 1) & 3)) << 3)];
    }
    #pragma unroll
    for (int i = 0; i < 4; ++i)
      #pragma unroll
      for (int j = 0; j < 4; ++j)
        acc[i][j] = __builtin_amdgcn_mfma_f32_16x16x32_bf16(a[i], b[j], acc[i][j], 0, 0, 0);
    __syncthreads();
  }
  // epilogue: D-frag lane holds row = 4*g+r, col = lo of each 16x16
  #pragma unroll
  for (int j = 0; j < 4; ++j) {
    int n = n0 + wn + j * 16 + lo;
    float bv = bias[n];
    #pragma unroll
    for (int i = 0; i < 4; ++i) {
      #pragma unroll
      for (int r = 0; r < 4; ++r) {
        int m = m0 + wm + i * 16 + g * 4 + r;
        float v = acc[i][j][r] + bv;
        if (EPI == 0) {
          int b_ = m >> 11, t = m & (Tt - 1);
          int h = n / 192, sub = n - h * 192;
          int which = sub >> 6, d = sub & 63;
          size_t idx = ((size_t)(b_ * Hh + h) * Tt + t) * HDd + d;
          if (which == 0)      Qb[idx] = f2bf(v * QSCALE);
          else if (which == 1) Kb[idx] = f2bf(v);
          else                 Vb[idx] = f2bf(v);
        } else {
          Cf[(size_t)m * N + n] = v;
        }
      }
    }
  }
}

// ---------------- flash attention (causal) ----------------
// grid (T/64, B*H), 256 threads = 4 waves; wave w owns q-rows [x*64+w*16, +16)
__global__ __launch_bounds__(256) void attn_kernel(const u16* __restrict__ Q,
                                                   const u16* __restrict__ K,
                                                   const u16* __restrict__ Vt,
                                                   u16* __restrict__ O) {
  __shared__ __align__(16) u16 Plds[4][512];  // per-wave 16x32 P scratch
  int bh = blockIdx.y;
  int b_ = bh >> 4, h = bh & 15;
  const u16* Qp = Q + (size_t)bh * Tt * HDd;
  const u16* Kp = K + (size_t)bh * Tt * HDd;
  const u16* Vp = Vt + (size_t)bh * HDd * Tt;
  int tid = threadIdx.x, w = tid >> 6, l = tid & 63;
  int lo = l & 15, g = l >> 4;
  int q0 = blockIdx.x * 64 + w * 16;
  bf16x8 aq[2];
  #pragma unroll
  for (int s = 0; s < 2; ++s)
    aq[s] = *(const bf16x8*)(Qp + (size_t)(q0 + lo) * HDd + s * 32 + g * 8);
  f32x4 o[4] = {};
  float M[4], L[4];
  #pragma unroll
  for (int r = 0; r < 4; ++r) { M[r] = -1e30f; L[r] = 0.f; }
  int kend = q0 + 16;
  for (int kt = 0; kt < kend; kt += 32) {
    f32x4 s0 = {}, s1 = {};
    #pragma unroll
    for (int ks = 0; ks < 2; ++ks) {
      bf16x8 bk0 = *(const bf16x8*)(Kp + (size_t)(kt + lo) * HDd + ks * 32 + g * 8);
      bf16x8 bk1 = *(const bf16x8*)(Kp + (size_t)(kt + 16 + lo) * HDd + ks * 32 + g * 8);
      s0 = __builtin_amdgcn_mfma_f32_16x16x32_bf16(aq[ks], bk0, s0, 0, 0, 0);
      s1 = __builtin_amdgcn_mfma_f32_16x16x32_bf16(aq[ks], bk1, s1, 0, 0, 0);
    }
    if (kt + 31 > q0) {   // tile touches the diagonal -> mask
      #pragma unroll
      for (int r = 0; r < 4; ++r) {
        int row = q0 + g * 4 + r;
        if (kt + lo > row)      s0[r] = -INFINITY;
        if (kt + 16 + lo > row) s1[r] = -INFINITY;
      }
    }
    float mloc[4], Mn[4], sc[4], p0[4], p1[4], ls[4];
    #pragma unroll
    for (int r = 0; r < 4; ++r) mloc[r] = fmaxf(s0[r], s1[r]);
    #pragma unroll
    for (int off = 1; off < 16; off <<= 1)
      #pragma unroll
      for (int r = 0; r < 4; ++r) mloc[r] = fmaxf(mloc[r], __shfl_xor(mloc[r], off));
    #pragma unroll
    for (int r = 0; r < 4; ++r) {
      Mn[r] = fmaxf(M[r], mloc[r]);
      sc[r] = exp2f(M[r] - Mn[r]);
      p0[r] = exp2f(s0[r] - Mn[r]);
      p1[r] = exp2f(s1[r] - Mn[r]);
      ls[r] = p0[r] + p1[r];
    }
    #pragma unroll
    for (int off = 1; off < 16; off <<= 1)
      #pragma unroll
      for (int r = 0; r < 4; ++r) ls[r] += __shfl_xor(ls[r], off);
    #pragma unroll
    for (int r = 0; r < 4; ++r) { L[r] = L[r] * sc[r] + ls[r]; M[r] = Mn[r]; }
    #pragma unroll
    for (int d = 0; d < 4; ++d)
      #pragma unroll
      for (int r = 0; r < 4; ++r) o[d][r] *= sc[r];
    // P (16x32) -> LDS -> A-frag
    #pragma unroll
    for (int r = 0; r < 4; ++r) {
      Plds[w][(g * 4 + r) * 32 + lo]      = f2bf(p0[r]);
      Plds[w][(g * 4 + r) * 32 + 16 + lo] = f2bf(p1[r]);
    }
    asm volatile("s_waitcnt lgkmcnt(0)" ::: "memory");
    bf16x8 ap = *(const bf16x8*)&Plds[w][lo * 32 + g * 8];
    #pragma unroll
    for (int d = 0; d < 4; ++d) {
      bf16x8 bv = *(const bf16x8*)(Vp + (size_t)(d * 16 + lo) * Tt + kt + g * 8);
      o[d] = __builtin_amdgcn_mfma_f32_16x16x32_bf16(ap, bv, o[d], 0, 0, 0);
    }
  }
  #pragma unroll
  for (int r = 0; r < 4; ++r) {
    float inv = 1.0f / L[r];
    int trow = q0 + g * 4 + r;
    size_t rowbase = ((size_t)b_ * Tt + trow) * Dd + h * HDd;
    #pragma unroll
    for (int d = 0; d < 4; ++d)
      O[rowbase + d * 16 + lo] = f2bf(o[d][r] * inv);
  }
}

extern "C" void kernel_launch(void* const* d_in, const int* in_sizes, int n_in,
                              void* d_out, int out_size, void* d_ws, size_t ws_size,
                              hipStream_t stream) {
  const float* x    = (const float*)d_in[0];
  const float* Wqkv = (const float*)d_in[1];
  const float* bqkv = (const float*)d_in[2];
  const float* Wout = (const float*)d_in[3];
  const float* bout = (const float*)d_in[4];
  float* out = (float*)d_out;
  char* ws = (char*)d_ws;

  // workspace layout (bytes); xb aliases Vt (xb dead after gemm1), V aliases O
  u16* xb    = (u16*)(ws + 0);           // 16,777,216
  u16* Wqkvt = (u16*)(ws + 16777216);    //  6,291,456
  u16* Woutt = (u16*)(ws + 23068672);    //  2,097,152
  u16* Qb    = (u16*)(ws + 25165824);    // 16,777,216
  u16* Kb    = (u16*)(ws + 41943040);    // 16,777,216
  u16* Vb    = (u16*)(ws + 58720256);    // 16,777,216
  u16* Vtb   = (u16*)(ws + 0);           // alias xb
  u16* Ob    = (u16*)(ws + 58720256);    // alias Vb
  // total required: 75,497,472 bytes

  cast_x_kernel<<<4096, 256, 0, stream>>>(x, xb, (MM * Dd) / 8);
  wcast_t_kernel<<<dim3(96, 32), 256, 0, stream>>>(Wqkv, Wqkvt, Dd, 3 * Dd);
  wcast_t_kernel<<<dim3(32, 32), 256, 0, stream>>>(Wout, Woutt, Dd, Dd);
  gemm_bt_kernel<0><<<dim3(24, 64), 256, 0, stream>>>(
      xb, Wqkvt, bqkv, nullptr, Qb, Kb, Vb, MM, 3 * Dd, Dd);
  vtrans_kernel<<<dim3(Tt / 32, HDd / 32, Bb * Hh), 256, 0, stream>>>(Vb, Vtb);
  attn_kernel<<<dim3(Tt / 64, Bb * Hh), 256, 0, stream>>>(Qb, Kb, Vtb, Ob);
  gemm_bt_kernel<1><<<dim3(8, 64), 256, 0, stream>>>(
      Ob, Woutt, bout, out, nullptr, nullptr, nullptr, MM, Dd, Dd);
}

// Round 2
// 375.616 us; speedup vs baseline: 1.5302x; 1.5302x over previous
//
#include <hip/hip_runtime.h>

typedef unsigned short u16;
typedef __bf16 bf16x8 __attribute__((ext_vector_type(8)));
typedef float f32x4 __attribute__((ext_vector_type(4)));

#define DEV __device__ __forceinline__

constexpr int Bb = 4, Tt = 2048, Dd = 1024, Hh = 16, HDd = 64;
constexpr int MM = Bb * Tt;        // 8192
constexpr float QSCALE = 0.125f * 1.4426950408889634f;  // 1/sqrt(64) * log2(e)

DEV u16 f2bf(float f) {
  unsigned u = __float_as_uint(f);
  u += 0x7fffu + ((u >> 16) & 1u);   // RNE
  return (u16)(u >> 16);
}

DEV void gload_lds16(const u16* g, u16* l) {
  __builtin_amdgcn_global_load_lds(
      (const __attribute__((address_space(1))) void*)g,
      (__attribute__((address_space(3))) void*)l, 16, 0, 0);
}

// ---------------- cast x -> bf16 ----------------
__global__ __launch_bounds__(256) void cast_x_kernel(const float* __restrict__ in,
                                                     u16* __restrict__ out, int n8) {
  int i = blockIdx.x * 256 + threadIdx.x;
  if (i >= n8) return;
  const float4* p = (const float4*)in + (size_t)i * 2;
  float4 v0 = p[0], v1 = p[1];
  union { u16 u[8]; uint4 v; } t;
  t.u[0] = f2bf(v0.x); t.u[1] = f2bf(v0.y); t.u[2] = f2bf(v0.z); t.u[3] = f2bf(v0.w);
  t.u[4] = f2bf(v1.x); t.u[5] = f2bf(v1.y); t.u[6] = f2bf(v1.z); t.u[7] = f2bf(v1.w);
  ((uint4*)out)[i] = t.v;
}

// ---------- cast + transpose weights: [K][N] f32 -> [N][K] bf16 ----------
__global__ __launch_bounds__(256) void wcast_t_kernel(const float* __restrict__ in,
                                                      u16* __restrict__ out, int K, int N) {
  __shared__ float tile[32][33];
  int n0 = blockIdx.x * 32, k0 = blockIdx.y * 32;
  int tx = threadIdx.x & 31, ty = threadIdx.x >> 5;
  #pragma unroll
  for (int yy = ty; yy < 32; yy += 8)
    tile[yy][tx] = in[(size_t)(k0 + yy) * N + n0 + tx];
  __syncthreads();
  #pragma unroll
  for (int yy = ty; yy < 32; yy += 8)
    out[(size_t)(n0 + yy) * K + k0 + tx] = f2bf(tile[tx][yy]);
}

// ---------------- V [bh][t][d] -> Vt [bh][d][t] (bf16) ----------------
__global__ __launch_bounds__(256) void vtrans_kernel(const u16* __restrict__ V,
                                                     u16* __restrict__ Vt) {
  __shared__ u16 tile[32][33];
  size_t base = (size_t)blockIdx.z * Tt * HDd;
  int t0 = blockIdx.x * 32, d0 = blockIdx.y * 32;
  int tx = threadIdx.x & 31, ty = threadIdx.x >> 5;
  #pragma unroll
  for (int yy = ty; yy < 32; yy += 8)
    tile[yy][tx] = V[base + (size_t)(t0 + yy) * HDd + d0 + tx];
  __syncthreads();
  #pragma unroll
  for (int yy = ty; yy < 32; yy += 8)
    Vt[base + (size_t)(d0 + yy) * Tt + t0 + tx] = tile[tx][yy];
}

// ---------------- GEMM: A[M][K] bf16 * Bt[N][K] bf16 ----------------
// 128x128 tile, BK=32, 4 waves 2x2. global_load_lds width16, double-buffered.
// LDS slot-swizzle: 16B slot s at row r holds k-slot (s ^ ((r>>1)&3)).
DEV void stage_tile(const u16* __restrict__ src, int row0, int k0, int ld, u16* lds) {
  int t = threadIdx.x, w = t >> 6;
  #pragma unroll
  for (int j = 0; j < 2; ++j) {
    int e = (j * 256 + t) * 8;
    int r = e >> 5;
    int slot = (e >> 3) & 3;
    int c = (slot ^ ((r >> 1) & 3)) << 3;
    gload_lds16(src + (size_t)(row0 + r) * ld + k0 + c, lds + j * 2048 + w * 512);
  }
}

template <int EPI>   // 0: QKV scatter epilogue, 1: plain f32 + bias
__global__ __launch_bounds__(256) void gemm_bt_kernel(
    const u16* __restrict__ A, const u16* __restrict__ Bt,
    const float* __restrict__ bias, float* __restrict__ Cf,
    u16* __restrict__ Qb, u16* __restrict__ Kb, u16* __restrict__ Vb,
    int M, int N, int Kd) {
  __shared__ __align__(16) u16 As[2][4096];
  __shared__ __align__(16) u16 Bs[2][4096];
  int m0 = blockIdx.y * 128, n0 = blockIdx.x * 128;
  int tid = threadIdx.x, l = tid & 63, w = tid >> 6;
  int lo = l & 15, g = l >> 4;
  int wm = (w >> 1) * 64, wn = (w & 1) * 64;
  f32x4 acc[4][4] = {};
  stage_tile(A, m0, 0, Kd, As[0]);
  stage_tile(Bt, n0, 0, Kd, Bs[0]);
  __syncthreads();
  int nk = Kd >> 5;
  for (int kt = 0; kt < nk; ++kt) {
    int cur = kt & 1;
    if (kt + 1 < nk) {
      stage_tile(A, m0, (kt + 1) * 32, Kd, As[cur ^ 1]);
      stage_tile(Bt, n0, (kt + 1) * 32, Kd, Bs[cur ^ 1]);
    }
    bf16x8 a[4], b[4];
    #pragma unroll
    for (int i = 0; i < 4; ++i) {
      int row = wm + i * 16 + lo;
      a[i] = *(const bf16x8*)&As[cur][row * 32 + ((g ^ ((row >> 1) & 3)) << 3)];
    }
    #pragma unroll
    for (int j = 0; j < 4; ++j) {
      int row = wn + j * 16 + lo;
      b[j] = *(const bf16x8*)&Bs[cur][row * 32 + ((g ^ ((row >> 1) & 3)) << 3)];
    }
    #pragma unroll
    for (int i = 0; i < 4; ++i)
      #pragma unroll
      for (int j = 0; j < 4; ++j)
        acc[i][j] = __builtin_amdgcn_mfma_f32_16x16x32_bf16(a[i], b[j], acc[i][j], 0, 0, 0);
    __syncthreads();
  }
  // epilogue: D-frag lane holds row = 4*g+r, col = lo of each 16x16
  #pragma unroll
  for (int j = 0; j < 4; ++j) {
    int n = n0 + wn + j * 16 + lo;
    float bv = bias[n];
    #pragma unroll
    for (int i = 0; i < 4; ++i) {
      #pragma unroll
      for (int r = 0; r < 4; ++r) {
        int m = m0 + wm + i * 16 + g * 4 + r;
        float v = acc[i][j][r] + bv;
        if (EPI == 0) {
          int b_ = m >> 11, t = m & (Tt - 1);
          int h = n / 192, sub = n - h * 192;
          int which = sub >> 6, d = sub & 63;
          size_t idx = ((size_t)(b_ * Hh + h) * Tt + t) * HDd + d;
          if (which == 0)      Qb[idx] = f2bf(v * QSCALE);
          else if (which == 1) Kb[idx] = f2bf(v);
          else                 Vb[idx] = f2bf(v);
        } else {
          Cf[(size_t)m * N + n] = v;
        }
      }
    }
  }
}

// ---------------- flash attention (causal), LDS-staged ----------------
// grid (T/128, B*H), 256 threads = 4 waves; wave w owns q-rows [qb+w*32, +32)
// K tile [64 t][64 d], Vt tile [64 d][64 t] staged via global_load_lds,
// double-buffered, XOR slot-swizzle (16B slot s at row r stored at s^(r&7)).
DEV void stage64x64(const u16* __restrict__ g, size_t rstride, u16* lds) {
  int t = threadIdx.x, w = t >> 6;
  #pragma unroll
  for (int j = 0; j < 2; ++j) {
    int e = j * 256 + t;
    int r = e >> 3, p = e & 7;
    int lg = p ^ (r & 7);
    gload_lds16(g + (size_t)r * rstride + lg * 8, lds + (size_t)(j * 256 + w * 64) * 8);
  }
}

__global__ __launch_bounds__(256) void attn_kernel(const u16* __restrict__ Q,
                                                   const u16* __restrict__ K,
                                                   const u16* __restrict__ Vt,
                                                   u16* __restrict__ O) {
  __shared__ __align__(16) u16 Ks[2][64 * 64];
  __shared__ __align__(16) u16 Vs[2][64 * 64];
  __shared__ __align__(16) u16 Plds[4][32 * 64];
  int bh = blockIdx.y;
  int b_ = bh >> 4, h = bh & 15;
  const u16* Qp = Q + (size_t)bh * Tt * HDd;
  const u16* Kp = K + (size_t)bh * Tt * HDd;
  const u16* Vp = Vt + (size_t)bh * HDd * Tt;
  int tid = threadIdx.x, w = tid >> 6, l = tid & 63;
  int lo = l & 15, g = l >> 4;
  int qb = ((int)gridDim.x - 1 - (int)blockIdx.x) * 128;   // heavy blocks first
  int q0 = qb + w * 32;

  bf16x8 aq[2][2];
  #pragma unroll
  for (int qf = 0; qf < 2; ++qf)
    #pragma unroll
    for (int ks = 0; ks < 2; ++ks)
      aq[qf][ks] = *(const bf16x8*)(Qp + (size_t)(q0 + qf * 16 + lo) * HDd + ks * 32 + g * 8);

  f32x4 o[2][4] = {};
  float M[2][4], L[2][4];
  #pragma unroll
  for (int qf = 0; qf < 2; ++qf)
    #pragma unroll
    for (int r = 0; r < 4; ++r) { M[qf][r] = -1e30f; L[qf][r] = 0.f; }

  int nt = qb / 64 + 2;
  stage64x64(Kp, HDd, Ks[0]);
  stage64x64(Vp, Tt, Vs[0]);
  __syncthreads();

  for (int it = 0; it < nt; ++it) {
    int cur = it & 1, kt = it * 64;
    if (it + 1 < nt) {
      stage64x64(Kp + (size_t)(kt + 64) * HDd, HDd, Ks[cur ^ 1]);
      stage64x64(Vp + kt + 64, Tt, Vs[cur ^ 1]);
    }
    if (kt < q0 + 32) {
      // ---- QK^T ----
      f32x4 sfr[2][4] = {};
      #pragma unroll
      for (int ks = 0; ks < 2; ++ks) {
        bf16x8 bk[4];
        #pragma unroll
        for (int ksub = 0; ksub < 4; ++ksub) {
          int row = ksub * 16 + lo;
          bk[ksub] = *(const bf16x8*)&Ks[cur][row * 64 + (((ks * 4 + g) ^ (row & 7)) << 3)];
        }
        #pragma unroll
        for (int qf = 0; qf < 2; ++qf)
          #pragma unroll
          for (int ksub = 0; ksub < 4; ++ksub)
            sfr[qf][ksub] = __builtin_amdgcn_mfma_f32_16x16x32_bf16(aq[qf][ks], bk[ksub], sfr[qf][ksub], 0, 0, 0);
      }
      // ---- causal mask (only diagonal-touching tiles) ----
      if (kt + 63 > q0) {
        #pragma unroll
        for (int qf = 0; qf < 2; ++qf)
          #pragma unroll
          for (int ksub = 0; ksub < 4; ++ksub)
            #pragma unroll
            for (int r = 0; r < 4; ++r) {
              int row = q0 + qf * 16 + g * 4 + r;
              if (kt + ksub * 16 + lo > row) sfr[qf][ksub][r] = -INFINITY;
            }
      }
      // ---- online softmax ----
      float sc[2][4];
      #pragma unroll
      for (int qf = 0; qf < 2; ++qf) {
        float mx[4], ls[4], ps[4][4];
        #pragma unroll
        for (int r = 0; r < 4; ++r)
          mx[r] = fmaxf(fmaxf(sfr[qf][0][r], sfr[qf][1][r]),
                        fmaxf(sfr[qf][2][r], sfr[qf][3][r]));
        #pragma unroll
        for (int off = 1; off < 16; off <<= 1)
          #pragma unroll
          for (int r = 0; r < 4; ++r) mx[r] = fmaxf(mx[r], __shfl_xor(mx[r], off));
        #pragma unroll
        for (int r = 0; r < 4; ++r) {
          float Mn = fmaxf(M[qf][r], mx[r]);
          sc[qf][r] = exp2f(M[qf][r] - Mn);
          M[qf][r] = Mn;
        }
        #pragma unroll
        for (int ksub = 0; ksub < 4; ++ksub)
          #pragma unroll
          for (int r = 0; r < 4; ++r)
            ps[ksub][r] = exp2f(sfr[qf][ksub][r] - M[qf][r]);
        #pragma unroll
        for (int r = 0; r < 4; ++r)
          ls[r] = (ps[0][r] + ps[1][r]) + (ps[2][r] + ps[3][r]);
        #pragma unroll
        for (int off = 1; off < 16; off <<= 1)
          #pragma unroll
          for (int r = 0; r < 4; ++r) ls[r] += __shfl_xor(ls[r], off);
        #pragma unroll
        for (int r = 0; r < 4; ++r) L[qf][r] = L[qf][r] * sc[qf][r] + ls[r];
        // write P (swizzled)
        #pragma unroll
        for (int ksub = 0; ksub < 4; ++ksub)
          #pragma unroll
          for (int r = 0; r < 4; ++r) {
            int q = qf * 16 + g * 4 + r;
            int kk = ksub * 16 + lo;
            int phys = (kk >> 3) ^ (q & 7);
            Plds[w][q * 64 + phys * 8 + (kk & 7)] = f2bf(ps[ksub][r]);
          }
      }
      // rescale O
      #pragma unroll
      for (int qf = 0; qf < 2; ++qf)
        #pragma unroll
        for (int df = 0; df < 4; ++df)
          #pragma unroll
          for (int r = 0; r < 4; ++r) o[qf][df][r] *= sc[qf][r];
      asm volatile("s_waitcnt lgkmcnt(0)" ::: "memory");
      // ---- PV ----
      #pragma unroll
      for (int ks2 = 0; ks2 < 2; ++ks2) {
        bf16x8 bv[4];
        #pragma unroll
        for (int df = 0; df < 4; ++df) {
          int row = df * 16 + lo;
          bv[df] = *(const bf16x8*)&Vs[cur][row * 64 + (((ks2 * 4 + g) ^ (row & 7)) << 3)];
        }
        bf16x8 ap[2];
        #pragma unroll
        for (int qf = 0; qf < 2; ++qf) {
          int q = qf * 16 + lo;
          ap[qf] = *(const bf16x8*)&Plds[w][q * 64 + (((ks2 * 4 + g) ^ (q & 7)) << 3)];
        }
        #pragma unroll
        for (int qf = 0; qf < 2; ++qf)
          #pragma unroll
          for (int df = 0; df < 4; ++df)
            o[qf][df] = __builtin_amdgcn_mfma_f32_16x16x32_bf16(ap[qf], bv[df], o[qf][df], 0, 0, 0);
      }
    }
    __syncthreads();
  }

  #pragma unroll
  for (int qf = 0; qf < 2; ++qf)
    #pragma unroll
    for (int r = 0; r < 4; ++r) {
      float inv = 1.0f / L[qf][r];
      int trow = q0 + qf * 16 + g * 4 + r;
      size_t rowbase = ((size_t)b_ * Tt + trow) * Dd + h * HDd;
      #pragma unroll
      for (int df = 0; df < 4; ++df)
        O[rowbase + df * 16 + lo] = f2bf(o[qf][df][r] * inv);
    }
}

extern "C" void kernel_launch(void* const* d_in, const int* in_sizes, int n_in,
                              void* d_out, int out_size, void* d_ws, size_t ws_size,
                              hipStream_t stream) {
  const float* x    = (const float*)d_in[0];
  const float* Wqkv = (const float*)d_in[1];
  const float* bqkv = (const float*)d_in[2];
  const float* Wout = (const float*)d_in[3];
  const float* bout = (const float*)d_in[4];
  float* out = (float*)d_out;
  char* ws = (char*)d_ws;

  // workspace layout (bytes); xb aliases Vt (xb dead after gemm1), V aliases O
  u16* xb    = (u16*)(ws + 0);           // 16,777,216
  u16* Wqkvt = (u16*)(ws + 16777216);    //  6,291,456
  u16* Woutt = (u16*)(ws + 23068672);    //  2,097,152
  u16* Qb    = (u16*)(ws + 25165824);    // 16,777,216
  u16* Kb    = (u16*)(ws + 41943040);    // 16,777,216
  u16* Vb    = (u16*)(ws + 58720256);    // 16,777,216
  u16* Vtb   = (u16*)(ws + 0);           // alias xb
  u16* Ob    = (u16*)(ws + 58720256);    // alias Vb
  // total required: 75,497,472 bytes

  cast_x_kernel<<<4096, 256, 0, stream>>>(x, xb, (MM * Dd) / 8);
  wcast_t_kernel<<<dim3(96, 32), 256, 0, stream>>>(Wqkv, Wqkvt, Dd, 3 * Dd);
  wcast_t_kernel<<<dim3(32, 32), 256, 0, stream>>>(Wout, Woutt, Dd, Dd);
  gemm_bt_kernel<0><<<dim3(24, 64), 256, 0, stream>>>(
      xb, Wqkvt, bqkv, nullptr, Qb, Kb, Vb, MM, 3 * Dd, Dd);
  vtrans_kernel<<<dim3(Tt / 32, HDd / 32, Bb * Hh), 256, 0, stream>>>(Vb, Vtb);
  attn_kernel<<<dim3(Tt / 128, Bb * Hh), 256, 0, stream>>>(Qb, Kb, Vtb, Ob);
  gemm_bt_kernel<1><<<dim3(8, 64), 256, 0, stream>>>(
      Ob, Woutt, bout, out, nullptr, nullptr, nullptr, MM, Dd, Dd);
}

// Round 3
// 247.828 us; speedup vs baseline: 2.3193x; 1.5156x over previous
//
#include <hip/hip_runtime.h>

typedef unsigned short u16;
typedef __bf16 bf16x8 __attribute__((ext_vector_type(8)));
typedef float f32x4 __attribute__((ext_vector_type(4)));
typedef float f32x16 __attribute__((ext_vector_type(16)));

#define DEV __device__ __forceinline__

constexpr int Bb = 4, Tt = 2048, Dd = 1024, Hh = 16, HDd = 64;
constexpr int MM = Bb * Tt;        // 8192
constexpr float QSCALE = 0.125f * 1.4426950408889634f;  // 1/sqrt(64) * log2(e)

DEV u16 f2bf(float f) {
  unsigned u = __float_as_uint(f);
  u += 0x7fffu + ((u >> 16) & 1u);   // RNE
  return (u16)(u >> 16);
}

DEV unsigned cvtpk(float a, float b) {   // bf16(a) in lo16, bf16(b) in hi16
  unsigned r;
  asm("v_cvt_pk_bf16_f32 %0, %1, %2" : "=v"(r) : "v"(a), "v"(b));
  return r;
}

DEV void pswap(unsigned& a, unsigned& b) {  // a'=[a_lo,b_lo], b'=[a_hi,b_hi]
  asm("v_permlane32_swap_b32 %0, %1" : "+v"(a), "+v"(b));
}

DEV void gload_lds16(const u16* g, u16* l) {
  __builtin_amdgcn_global_load_lds(
      (const __attribute__((address_space(1))) void*)g,
      (__attribute__((address_space(3))) void*)l, 16, 0, 0);
}

// ---------------- cast x -> bf16 ----------------
__global__ __launch_bounds__(256) void cast_x_kernel(const float* __restrict__ in,
                                                     u16* __restrict__ out, int n8) {
  int i = blockIdx.x * 256 + threadIdx.x;
  if (i >= n8) return;
  const float4* p = (const float4*)in + (size_t)i * 2;
  float4 v0 = p[0], v1 = p[1];
  union { u16 u[8]; uint4 v; } t;
  t.u[0] = f2bf(v0.x); t.u[1] = f2bf(v0.y); t.u[2] = f2bf(v0.z); t.u[3] = f2bf(v0.w);
  t.u[4] = f2bf(v1.x); t.u[5] = f2bf(v1.y); t.u[6] = f2bf(v1.z); t.u[7] = f2bf(v1.w);
  ((uint4*)out)[i] = t.v;
}

// ---------- cast + transpose weights: [K][N] f32 -> [N][K] bf16 ----------
__global__ __launch_bounds__(256) void wcast_t_kernel(const float* __restrict__ in,
                                                      u16* __restrict__ out, int K, int N) {
  __shared__ float tile[32][33];
  int n0 = blockIdx.x * 32, k0 = blockIdx.y * 32;
  int tx = threadIdx.x & 31, ty = threadIdx.x >> 5;
  #pragma unroll
  for (int yy = ty; yy < 32; yy += 8)
    tile[yy][tx] = in[(size_t)(k0 + yy) * N + n0 + tx];
  __syncthreads();
  #pragma unroll
  for (int yy = ty; yy < 32; yy += 8)
    out[(size_t)(n0 + yy) * K + k0 + tx] = f2bf(tile[tx][yy]);
}

// ---------------- V [bh][t][d] -> Vt [bh][d][t] (bf16) ----------------
__global__ __launch_bounds__(256) void vtrans_kernel(const u16* __restrict__ V,
                                                     u16* __restrict__ Vt) {
  __shared__ u16 tile[32][33];
  size_t base = (size_t)blockIdx.z * Tt * HDd;
  int t0 = blockIdx.x * 32, d0 = blockIdx.y * 32;
  int tx = threadIdx.x & 31, ty = threadIdx.x >> 5;
  #pragma unroll
  for (int yy = ty; yy < 32; yy += 8)
    tile[yy][tx] = V[base + (size_t)(t0 + yy) * HDd + d0 + tx];
  __syncthreads();
  #pragma unroll
  for (int yy = ty; yy < 32; yy += 8)
    Vt[base + (size_t)(d0 + yy) * Tt + t0 + tx] = tile[tx][yy];
}

// ---------------- GEMM: A[M][K] bf16 * Bt[N][K] bf16 ----------------
// 128x128 tile, BK=32, 4 waves 2x2. global_load_lds width16, double-buffered.
DEV void stage_tile(const u16* __restrict__ src, int row0, int k0, int ld, u16* lds) {
  int t = threadIdx.x, w = t >> 6;
  #pragma unroll
  for (int j = 0; j < 2; ++j) {
    int e = (j * 256 + t) * 8;
    int r = e >> 5;
    int slot = (e >> 3) & 3;
    int c = (slot ^ ((r >> 1) & 3)) << 3;
    gload_lds16(src + (size_t)(row0 + r) * ld + k0 + c, lds + j * 2048 + w * 512);
  }
}

template <int EPI>   // 0: QKV scatter epilogue, 1: plain f32 + bias
__global__ __launch_bounds__(256) void gemm_bt_kernel(
    const u16* __restrict__ A, const u16* __restrict__ Bt,
    const float* __restrict__ bias, float* __restrict__ Cf,
    u16* __restrict__ Qb, u16* __restrict__ Kb, u16* __restrict__ Vb,
    int M, int N, int Kd) {
  __shared__ __align__(16) u16 As[2][4096];
  __shared__ __align__(16) u16 Bs[2][4096];
  int m0 = blockIdx.y * 128, n0 = blockIdx.x * 128;
  int tid = threadIdx.x, l = tid & 63, w = tid >> 6;
  int lo = l & 15, g = l >> 4;
  int wm = (w >> 1) * 64, wn = (w & 1) * 64;
  f32x4 acc[4][4] = {};
  stage_tile(A, m0, 0, Kd, As[0]);
  stage_tile(Bt, n0, 0, Kd, Bs[0]);
  __syncthreads();
  int nk = Kd >> 5;
  for (int kt = 0; kt < nk; ++kt) {
    int cur = kt & 1;
    if (kt + 1 < nk) {
      stage_tile(A, m0, (kt + 1) * 32, Kd, As[cur ^ 1]);
      stage_tile(Bt, n0, (kt + 1) * 32, Kd, Bs[cur ^ 1]);
    }
    bf16x8 a[4], b[4];
    #pragma unroll
    for (int i = 0; i < 4; ++i) {
      int row = wm + i * 16 + lo;
      a[i] = *(const bf16x8*)&As[cur][row * 32 + ((g ^ ((row >> 1) & 3)) << 3)];
    }
    #pragma unroll
    for (int j = 0; j < 4; ++j) {
      int row = wn + j * 16 + lo;
      b[j] = *(const bf16x8*)&Bs[cur][row * 32 + ((g ^ ((row >> 1) & 3)) << 3)];
    }
    #pragma unroll
    for (int i = 0; i < 4; ++i)
      #pragma unroll
      for (int j = 0; j < 4; ++j)
        acc[i][j] = __builtin_amdgcn_mfma_f32_16x16x32_bf16(a[i], b[j], acc[i][j], 0, 0, 0);
    __syncthreads();
  }
  #pragma unroll
  for (int j = 0; j < 4; ++j) {
    int n = n0 + wn + j * 16 + lo;
    float bv = bias[n];
    #pragma unroll
    for (int i = 0; i < 4; ++i) {
      #pragma unroll
      for (int r = 0; r < 4; ++r) {
        int m = m0 + wm + i * 16 + g * 4 + r;
        float v = acc[i][j][r] + bv;
        if (EPI == 0) {
          int b_ = m >> 11, t = m & (Tt - 1);
          int h = n / 192, sub = n - h * 192;
          int which = sub >> 6, d = sub & 63;
          size_t idx = ((size_t)(b_ * Hh + h) * Tt + t) * HDd + d;
          if (which == 0)      Qb[idx] = f2bf(v * QSCALE);
          else if (which == 1) Kb[idx] = f2bf(v);
          else                 Vb[idx] = f2bf(v);
        } else {
          Cf[(size_t)m * N + n] = v;
        }
      }
    }
  }
}

// ---------------- flash attention (causal), swapped-QK^T 32x32 ----------------
// grid (T/128, B*H), 256 threads = 4 waves; wave w owns q-rows [qb+32w, +32).
// Lane holds q = lane&31; S^T = mfma32(K, Q^T) puts 32 k-vals in regs;
// softmax fully in-register; PV as O^T = mfma32(V^T, P^T).
DEV void stage64x64(const u16* __restrict__ g, size_t rstride, u16* lds) {
  int t = threadIdx.x, w = t >> 6;
  #pragma unroll
  for (int j = 0; j < 2; ++j) {
    int e = j * 256 + t;
    int r = e >> 3, p = e & 7;
    int lg = p ^ (r & 7);
    gload_lds16(g + (size_t)r * rstride + lg * 8, lds + (size_t)(j * 256 + w * 64) * 8);
  }
}

DEV void build_pfrags(const f32x16& s, bf16x8& f0, bf16x8& f1) {
  unsigned w0 = cvtpk(s[0], s[1]),  w1 = cvtpk(s[2], s[3]);
  unsigned w2 = cvtpk(s[4], s[5]),  w3 = cvtpk(s[6], s[7]);
  unsigned w4 = cvtpk(s[8], s[9]),  w5 = cvtpk(s[10], s[11]);
  unsigned w6 = cvtpk(s[12], s[13]), w7 = cvtpk(s[14], s[15]);
  pswap(w0, w2);  // w0 = D0, w2 = D2 (k-step 0)
  pswap(w1, w3);  // w1 = D1, w3 = D3
  pswap(w4, w6);  // k-step 1
  pswap(w5, w7);
  union { unsigned u[4]; bf16x8 v; } t0, t1;
  t0.u[0] = w0; t0.u[1] = w1; t0.u[2] = w2; t0.u[3] = w3;
  t1.u[0] = w4; t1.u[1] = w5; t1.u[2] = w6; t1.u[3] = w7;
  f0 = t0.v; f1 = t1.v;
}

__global__ __launch_bounds__(256) void attn_kernel(const u16* __restrict__ Q,
                                                   const u16* __restrict__ K,
                                                   const u16* __restrict__ Vt,
                                                   u16* __restrict__ O) {
  __shared__ __align__(16) u16 Ks[2][4096];
  __shared__ __align__(16) u16 Vs[2][4096];
  int bh = blockIdx.y;
  int b_ = bh >> 4, h = bh & 15;
  const u16* Qp = Q + (size_t)bh * Tt * HDd;
  const u16* Kp = K + (size_t)bh * Tt * HDd;
  const u16* Vp = Vt + (size_t)bh * HDd * Tt;
  int tid = threadIdx.x, w = tid >> 6, l = tid & 63;
  int lq = l & 31, hf = l >> 5;
  int qb = ((int)gridDim.x - 1 - (int)blockIdx.x) * 128;   // heavy blocks first
  int q0 = qb + w * 32;
  int qrow = q0 + lq;

  bf16x8 aq[4];
  #pragma unroll
  for (int s = 0; s < 4; ++s)
    aq[s] = *(const bf16x8*)(Qp + (size_t)qrow * HDd + s * 16 + hf * 8);

  f32x16 o0 = {}, o1 = {};
  float M = -1e30f, L = 0.f;

  int nt = qb / 64 + 2;
  stage64x64(Kp, HDd, Ks[0]);
  stage64x64(Vp, Tt, Vs[0]);
  __syncthreads();

  for (int it = 0; it < nt; ++it) {
    int cur = it & 1, kt = it * 64;
    if (it + 1 < nt) {
      stage64x64(Kp + (size_t)(kt + 64) * HDd, HDd, Ks[cur ^ 1]);
      stage64x64(Vp + (kt + 64), Tt, Vs[cur ^ 1]);
    }
    if (kt < q0 + 32) {
      // ---- S^T = K . Q^T : lane holds q=lq, k in regs ----
      f32x16 s0 = {}, s1 = {};
      int swz = lq & 7;
      __builtin_amdgcn_s_setprio(1);
      #pragma unroll
      for (int ds = 0; ds < 4; ++ds) {
        int slot = 2 * ds + hf;
        bf16x8 k0 = *(const bf16x8*)&Ks[cur][lq * 64 + ((slot ^ swz) << 3)];
        bf16x8 k1 = *(const bf16x8*)&Ks[cur][(32 + lq) * 64 + ((slot ^ swz) << 3)];
        s0 = __builtin_amdgcn_mfma_f32_32x32x16_bf16(k0, aq[ds], s0, 0, 0, 0);
        s1 = __builtin_amdgcn_mfma_f32_32x32x16_bf16(k1, aq[ds], s1, 0, 0, 0);
      }
      __builtin_amdgcn_s_setprio(0);
      // ---- causal mask (diagonal-touching tiles only) ----
      if (kt + 63 > q0) {
        #pragma unroll
        for (int r = 0; r < 16; ++r) {
          int kg = kt + (r & 3) + 8 * (r >> 2) + 4 * hf;
          if (kg > qrow)      s0[r] = -INFINITY;
          if (kg + 32 > qrow) s1[r] = -INFINITY;
        }
      }
      // ---- online softmax: in-lane tree + one cross-half shuffle ----
      float mx_[16];
      #pragma unroll
      for (int r = 0; r < 16; ++r) mx_[r] = fmaxf(s0[r], s1[r]);
      #pragma unroll
      for (int st = 8; st >= 1; st >>= 1)
        #pragma unroll
        for (int r = 0; r < 16; ++r) if (r < st) mx_[r] = fmaxf(mx_[r], mx_[r + st]);
      float mx = fmaxf(mx_[0], __shfl_xor(mx_[0], 32));
      float Mn = fmaxf(M, mx);
      float sc = __builtin_amdgcn_exp2f(M - Mn);
      M = Mn;
      #pragma unroll
      for (int r = 0; r < 16; ++r) {
        s0[r] = __builtin_amdgcn_exp2f(s0[r] - Mn);
        s1[r] = __builtin_amdgcn_exp2f(s1[r] - Mn);
      }
      float ls_[16];
      #pragma unroll
      for (int r = 0; r < 16; ++r) ls_[r] = s0[r] + s1[r];
      #pragma unroll
      for (int st = 8; st >= 1; st >>= 1)
        #pragma unroll
        for (int r = 0; r < 16; ++r) if (r < st) ls_[r] += ls_[r + st];
      float ls = ls_[0] + __shfl_xor(ls_[0], 32);
      L = L * sc + ls;
      // ---- P -> bf16 B-frags in-register (cvt_pk + permlane32_swap) ----
      bf16x8 pf0, pf1, pf2, pf3;
      build_pfrags(s0, pf0, pf1);
      build_pfrags(s1, pf2, pf3);
      // ---- rescale O ----
      #pragma unroll
      for (int r = 0; r < 16; ++r) { o0[r] *= sc; o1[r] *= sc; }
      // ---- O^T += V^T . P^T ----
      __builtin_amdgcn_s_setprio(1);
      #pragma unroll
      for (int ks = 0; ks < 4; ++ks) {
        int slot = 2 * ks + hf;
        bf16x8 v0 = *(const bf16x8*)&Vs[cur][lq * 64 + ((slot ^ swz) << 3)];
        bf16x8 v1 = *(const bf16x8*)&Vs[cur][(32 + lq) * 64 + ((slot ^ swz) << 3)];
        bf16x8 pf = (ks == 0) ? pf0 : (ks == 1) ? pf1 : (ks == 2) ? pf2 : pf3;
        o0 = __builtin_amdgcn_mfma_f32_32x32x16_bf16(v0, pf, o0, 0, 0, 0);
        o1 = __builtin_amdgcn_mfma_f32_32x32x16_bf16(v1, pf, o1, 0, 0, 0);
      }
      __builtin_amdgcn_s_setprio(0);
    }
    __syncthreads();
  }

  // ---- epilogue: lane owns row qrow; d = (r&3)+8(r>>2)+4hf (+32 for o1) ----
  float inv = 1.0f / L;
  size_t rowbase = ((size_t)b_ * Tt + qrow) * Dd + h * HDd;
  #pragma unroll
  for (int m = 0; m < 4; ++m) {
    uint2 v0, v1;
    v0.x = cvtpk(o0[4 * m] * inv,     o0[4 * m + 1] * inv);
    v0.y = cvtpk(o0[4 * m + 2] * inv, o0[4 * m + 3] * inv);
    *(uint2*)(O + rowbase + m * 8 + hf * 4) = v0;
    v1.x = cvtpk(o1[4 * m] * inv,     o1[4 * m + 1] * inv);
    v1.y = cvtpk(o1[4 * m + 2] * inv, o1[4 * m + 3] * inv);
    *(uint2*)(O + rowbase + 32 + m * 8 + hf * 4) = v1;
  }
}

extern "C" void kernel_launch(void* const* d_in, const int* in_sizes, int n_in,
                              void* d_out, int out_size, void* d_ws, size_t ws_size,
                              hipStream_t stream) {
  const float* x    = (const float*)d_in[0];
  const float* Wqkv = (const float*)d_in[1];
  const float* bqkv = (const float*)d_in[2];
  const float* Wout = (const float*)d_in[3];
  const float* bout = (const float*)d_in[4];
  float* out = (float*)d_out;
  char* ws = (char*)d_ws;

  u16* xb    = (u16*)(ws + 0);           // 16,777,216
  u16* Wqkvt = (u16*)(ws + 16777216);    //  6,291,456
  u16* Woutt = (u16*)(ws + 23068672);    //  2,097,152
  u16* Qb    = (u16*)(ws + 25165824);    // 16,777,216
  u16* Kb    = (u16*)(ws + 41943040);    // 16,777,216
  u16* Vb    = (u16*)(ws + 58720256);    // 16,777,216
  u16* Vtb   = (u16*)(ws + 0);           // alias xb
  u16* Ob    = (u16*)(ws + 58720256);    // alias Vb

  cast_x_kernel<<<4096, 256, 0, stream>>>(x, xb, (MM * Dd) / 8);
  wcast_t_kernel<<<dim3(96, 32), 256, 0, stream>>>(Wqkv, Wqkvt, Dd, 3 * Dd);
  wcast_t_kernel<<<dim3(32, 32), 256, 0, stream>>>(Wout, Woutt, Dd, Dd);
  gemm_bt_kernel<0><<<dim3(24, 64), 256, 0, stream>>>(
      xb, Wqkvt, bqkv, nullptr, Qb, Kb, Vb, MM, 3 * Dd, Dd);
  vtrans_kernel<<<dim3(Tt / 32, HDd / 32, Bb * Hh), 256, 0, stream>>>(Vb, Vtb);
  attn_kernel<<<dim3(Tt / 128, Bb * Hh), 256, 0, stream>>>(Qb, Kb, Vtb, Ob);
  gemm_bt_kernel<1><<<dim3(8, 64), 256, 0, stream>>>(
      Ob, Woutt, bout, out, nullptr, nullptr, nullptr, MM, Dd, Dd);
}

// Round 5
// 205.149 us; speedup vs baseline: 2.8018x; 1.2080x over previous
//
#include <hip/hip_runtime.h>

typedef unsigned short u16;
typedef __bf16 bf16x8 __attribute__((ext_vector_type(8)));
typedef float f32x4 __attribute__((ext_vector_type(4)));
typedef float f32x16 __attribute__((ext_vector_type(16)));

#define DEV __device__ __forceinline__

constexpr int Bb = 4, Tt = 2048, Dd = 1024, Hh = 16, HDd = 64;
constexpr int MM = Bb * Tt;        // 8192
constexpr float QSCALE = 0.125f * 1.4426950408889634f;  // 1/sqrt(64) * log2(e)

DEV u16 f2bf(float f) {
  unsigned u = __float_as_uint(f);
  u += 0x7fffu + ((u >> 16) & 1u);   // RNE
  return (u16)(u >> 16);
}

DEV unsigned cvtpk(float a, float b) {   // bf16(a) in lo16, bf16(b) in hi16
  unsigned r;
  asm("v_cvt_pk_bf16_f32 %0, %1, %2" : "=v"(r) : "v"(a), "v"(b));
  return r;
}

DEV void pswap(unsigned& a, unsigned& b) {  // half-exchange across lane 32 split
  asm("v_permlane32_swap_b32 %0, %1" : "+v"(a), "+v"(b));
}

DEV void gload_lds16(const u16* g, u16* l) {
  __builtin_amdgcn_global_load_lds(
      (const __attribute__((address_space(1))) void*)g,
      (__attribute__((address_space(3))) void*)l, 16, 0, 0);
}

// ---------------- cast x -> bf16 ----------------
__global__ __launch_bounds__(256) void cast_x_kernel(const float* __restrict__ in,
                                                     u16* __restrict__ out, int n8) {
  int i = blockIdx.x * 256 + threadIdx.x;
  if (i >= n8) return;
  const float4* p = (const float4*)in + (size_t)i * 2;
  float4 v0 = p[0], v1 = p[1];
  union { u16 u[8]; uint4 v; } t;
  t.u[0] = f2bf(v0.x); t.u[1] = f2bf(v0.y); t.u[2] = f2bf(v0.z); t.u[3] = f2bf(v0.w);
  t.u[4] = f2bf(v1.x); t.u[5] = f2bf(v1.y); t.u[6] = f2bf(v1.z); t.u[7] = f2bf(v1.w);
  ((uint4*)out)[i] = t.v;
}

// ---------- cast + transpose weights: [K][N] f32 -> [N][K] bf16 ----------
__global__ __launch_bounds__(256) void wcast_t_kernel(const float* __restrict__ in,
                                                      u16* __restrict__ out, int K, int N) {
  __shared__ float tile[32][33];
  int n0 = blockIdx.x * 32, k0 = blockIdx.y * 32;
  int tx = threadIdx.x & 31, ty = threadIdx.x >> 5;
  #pragma unroll
  for (int yy = ty; yy < 32; yy += 8)
    tile[yy][tx] = in[(size_t)(k0 + yy) * N + n0 + tx];
  __syncthreads();
  #pragma unroll
  for (int yy = ty; yy < 32; yy += 8)
    out[(size_t)(n0 + yy) * K + k0 + tx] = f2bf(tile[tx][yy]);
}

// ---------------- V [bh][t][d] -> Vt [bh][d][t] (bf16) ----------------
__global__ __launch_bounds__(256) void vtrans_kernel(const u16* __restrict__ V,
                                                     u16* __restrict__ Vt) {
  __shared__ u16 tile[32][33];
  size_t base = (size_t)blockIdx.z * Tt * HDd;
  int t0 = blockIdx.x * 32, d0 = blockIdx.y * 32;
  int tx = threadIdx.x & 31, ty = threadIdx.x >> 5;
  #pragma unroll
  for (int yy = ty; yy < 32; yy += 8)
    tile[yy][tx] = V[base + (size_t)(t0 + yy) * HDd + d0 + tx];
  __syncthreads();
  #pragma unroll
  for (int yy = ty; yy < 32; yy += 8)
    Vt[base + (size_t)(d0 + yy) * Tt + t0 + tx] = tile[tx][yy];
}

// ---------------- GEMM: A[M][K] bf16 * Bt[N][K] bf16 ----------------
DEV void stage_tile(const u16* __restrict__ src, int row0, int k0, int ld, u16* lds) {
  int t = threadIdx.x, w = t >> 6;
  #pragma unroll
  for (int j = 0; j < 2; ++j) {
    int e = (j * 256 + t) * 8;
    int r = e >> 5;
    int slot = (e >> 3) & 3;
    int c = (slot ^ ((r >> 1) & 3)) << 3;
    gload_lds16(src + (size_t)(row0 + r) * ld + k0 + c, lds + j * 2048 + w * 512);
  }
}

template <int EPI>   // 0: QKV scatter epilogue, 1: plain f32 + bias
__global__ __launch_bounds__(256) void gemm_bt_kernel(
    const u16* __restrict__ A, const u16* __restrict__ Bt,
    const float* __restrict__ bias, float* __restrict__ Cf,
    u16* __restrict__ Qb, u16* __restrict__ Kb, u16* __restrict__ Vb,
    int M, int N, int Kd) {
  __shared__ __align__(16) u16 As[2][4096];
  __shared__ __align__(16) u16 Bs[2][4096];
  int m0 = blockIdx.y * 128, n0 = blockIdx.x * 128;
  int tid = threadIdx.x, l = tid & 63, w = tid >> 6;
  int lo = l & 15, g = l >> 4;
  int wm = (w >> 1) * 64, wn = (w & 1) * 64;
  f32x4 acc[4][4] = {};
  stage_tile(A, m0, 0, Kd, As[0]);
  stage_tile(Bt, n0, 0, Kd, Bs[0]);
  __syncthreads();
  int nk = Kd >> 5;
  for (int kt = 0; kt < nk; ++kt) {
    int cur = kt & 1;
    if (kt + 1 < nk) {
      stage_tile(A, m0, (kt + 1) * 32, Kd, As[cur ^ 1]);
      stage_tile(Bt, n0, (kt + 1) * 32, Kd, Bs[cur ^ 1]);
    }
    bf16x8 a[4], b[4];
    #pragma unroll
    for (int i = 0; i < 4; ++i) {
      int row = wm + i * 16 + lo;
      a[i] = *(const bf16x8*)&As[cur][row * 32 + ((g ^ ((row >> 1) & 3)) << 3)];
    }
    #pragma unroll
    for (int j = 0; j < 4; ++j) {
      int row = wn + j * 16 + lo;
      b[j] = *(const bf16x8*)&Bs[cur][row * 32 + ((g ^ ((row >> 1) & 3)) << 3)];
    }
    #pragma unroll
    for (int i = 0; i < 4; ++i)
      #pragma unroll
      for (int j = 0; j < 4; ++j)
        acc[i][j] = __builtin_amdgcn_mfma_f32_16x16x32_bf16(a[i], b[j], acc[i][j], 0, 0, 0);
    __syncthreads();
  }
  #pragma unroll
  for (int j = 0; j < 4; ++j) {
    int n = n0 + wn + j * 16 + lo;
    float bv = bias[n];
    #pragma unroll
    for (int i = 0; i < 4; ++i) {
      #pragma unroll
      for (int r = 0; r < 4; ++r) {
        int m = m0 + wm + i * 16 + g * 4 + r;
        float v = acc[i][j][r] + bv;
        if (EPI == 0) {
          int b_ = m >> 11, t = m & (Tt - 1);
          int h = n / 192, sub = n - h * 192;
          int which = sub >> 6, d = sub & 63;
          size_t idx = ((size_t)(b_ * Hh + h) * Tt + t) * HDd + d;
          if (which == 0)      Qb[idx] = f2bf(v * QSCALE);
          else if (which == 1) Kb[idx] = f2bf(v);
          else                 Vb[idx] = f2bf(v);
        } else {
          Cf[(size_t)m * N + n] = v;
        }
      }
    }
  }
}

// ---------------- flash attention (causal), paired q-blocks ----------------
// grid (8, B*H), 256 threads = 4 waves. Block p handles q-block JA=15-p then
// JB=p (128 rows each): ntA+ntB = 34 k-tiles for EVERY block -> perfect
// balance. Softmax body is R3's verbatim (unconditional rescale, shfl_xor) --
// R4's defer-max + permlane reduce are reverted pending bisection.
DEV void stage64x64(const u16* __restrict__ g, size_t rstride, u16* lds) {
  int t = threadIdx.x, w = t >> 6;
  #pragma unroll
  for (int j = 0; j < 2; ++j) {
    int e = j * 256 + t;
    int r = e >> 3, p = e & 7;
    int lg = p ^ (r & 7);
    gload_lds16(g + (size_t)r * rstride + lg * 8, lds + (size_t)(j * 256 + w * 64) * 8);
  }
}

DEV void build_pfrags(const f32x16& s, bf16x8& f0, bf16x8& f1) {
  unsigned w0 = cvtpk(s[0], s[1]),  w1 = cvtpk(s[2], s[3]);
  unsigned w2 = cvtpk(s[4], s[5]),  w3 = cvtpk(s[6], s[7]);
  unsigned w4 = cvtpk(s[8], s[9]),  w5 = cvtpk(s[10], s[11]);
  unsigned w6 = cvtpk(s[12], s[13]), w7 = cvtpk(s[14], s[15]);
  pswap(w0, w2);
  pswap(w1, w3);
  pswap(w4, w6);
  pswap(w5, w7);
  union { unsigned u[4]; bf16x8 v; } t0, t1;
  t0.u[0] = w0; t0.u[1] = w1; t0.u[2] = w2; t0.u[3] = w3;
  t1.u[0] = w4; t1.u[1] = w5; t1.u[2] = w6; t1.u[3] = w7;
  f0 = t0.v; f1 = t1.v;
}

DEV void write_o(u16* __restrict__ O, size_t rowbase, const f32x16& o0,
                 const f32x16& o1, float L, int hf) {
  float inv = 1.0f / L;
  #pragma unroll
  for (int m = 0; m < 4; ++m) {
    uint2 v0, v1;
    v0.x = cvtpk(o0[4 * m] * inv,     o0[4 * m + 1] * inv);
    v0.y = cvtpk(o0[4 * m + 2] * inv, o0[4 * m + 3] * inv);
    *(uint2*)(O + rowbase + m * 8 + hf * 4) = v0;
    v1.x = cvtpk(o1[4 * m] * inv,     o1[4 * m + 1] * inv);
    v1.y = cvtpk(o1[4 * m + 2] * inv, o1[4 * m + 3] * inv);
    *(uint2*)(O + rowbase + 32 + m * 8 + hf * 4) = v1;
  }
}

__global__ __launch_bounds__(256) void attn_kernel(const u16* __restrict__ Q,
                                                   const u16* __restrict__ K,
                                                   const u16* __restrict__ Vt,
                                                   u16* __restrict__ O) {
  __shared__ __align__(16) u16 Ks[2][4096];
  __shared__ __align__(16) u16 Vs[2][4096];
  int bh = blockIdx.y;
  int b_ = bh >> 4, h = bh & 15;
  const u16* Qp = Q + (size_t)bh * Tt * HDd;
  const u16* Kp = K + (size_t)bh * Tt * HDd;
  const u16* Vp = Vt + (size_t)bh * HDd * Tt;
  int tid = threadIdx.x, w = tid >> 6, l = tid & 63;
  int lq = l & 31, hf = l >> 5;
  int p = blockIdx.x;
  int JA = 15 - p, JB = p;
  int ntA = 2 * JA + 2, ntB = 2 * JB + 2, ntT = ntA + ntB;   // == 34

  int q0 = 128 * JA + 32 * w;
  int qrow = q0 + lq;

  bf16x8 aq[4];
  #pragma unroll
  for (int s = 0; s < 4; ++s)
    aq[s] = *(const bf16x8*)(Qp + (size_t)qrow * HDd + s * 16 + hf * 8);

  f32x16 o0 = {}, o1 = {};
  float M = -1e30f, L = 0.f;

  stage64x64(Kp, HDd, Ks[0]);
  stage64x64(Vp, Tt, Vs[0]);
  __syncthreads();

  for (int it = 0; it < ntT; ++it) {
    if (it == ntA) {
      // finalize pass A, switch to pass B
      size_t rbA = ((size_t)b_ * Tt + qrow) * Dd + h * HDd;
      write_o(O, rbA, o0, o1, L, hf);
      #pragma unroll
      for (int r = 0; r < 16; ++r) { o0[r] = 0.f; o1[r] = 0.f; }
      M = -1e30f; L = 0.f;
      q0 = 128 * JB + 32 * w;
      qrow = q0 + lq;
      #pragma unroll
      for (int s = 0; s < 4; ++s)
        aq[s] = *(const bf16x8*)(Qp + (size_t)qrow * HDd + s * 16 + hf * 8);
    }
    int kt = (it < ntA ? it : it - ntA) * 64;
    int cur = it & 1;
    if (it + 1 < ntT) {
      int nkt = (it + 1 < ntA ? it + 1 : it + 1 - ntA) * 64;
      stage64x64(Kp + (size_t)nkt * HDd, HDd, Ks[cur ^ 1]);
      stage64x64(Vp + nkt, Tt, Vs[cur ^ 1]);
    }
    if (kt < q0 + 32) {
      // ---- S^T = K . Q^T ----
      f32x16 s0 = {}, s1 = {};
      int swz = lq & 7;
      __builtin_amdgcn_s_setprio(1);
      #pragma unroll
      for (int ds = 0; ds < 4; ++ds) {
        int slot = 2 * ds + hf;
        bf16x8 k0 = *(const bf16x8*)&Ks[cur][lq * 64 + ((slot ^ swz) << 3)];
        bf16x8 k1 = *(const bf16x8*)&Ks[cur][(32 + lq) * 64 + ((slot ^ swz) << 3)];
        s0 = __builtin_amdgcn_mfma_f32_32x32x16_bf16(k0, aq[ds], s0, 0, 0, 0);
        s1 = __builtin_amdgcn_mfma_f32_32x32x16_bf16(k1, aq[ds], s1, 0, 0, 0);
      }
      __builtin_amdgcn_s_setprio(0);
      // ---- causal mask (diagonal-touching tiles only) ----
      if (kt + 63 > q0) {
        #pragma unroll
        for (int r = 0; r < 16; ++r) {
          int kg = kt + (r & 3) + 8 * (r >> 2) + 4 * hf;
          if (kg > qrow)      s0[r] = -INFINITY;
          if (kg + 32 > qrow) s1[r] = -INFINITY;
        }
      }
      // ---- online softmax: in-lane tree + one cross-half shuffle (R3) ----
      float mx_[16];
      #pragma unroll
      for (int r = 0; r < 16; ++r) mx_[r] = fmaxf(s0[r], s1[r]);
      #pragma unroll
      for (int st = 8; st >= 1; st >>= 1)
        #pragma unroll
        for (int r = 0; r < 16; ++r) if (r < st) mx_[r] = fmaxf(mx_[r], mx_[r + st]);
      float mx = fmaxf(mx_[0], __shfl_xor(mx_[0], 32));
      float Mn = fmaxf(M, mx);
      float sc = __builtin_amdgcn_exp2f(M - Mn);
      M = Mn;
      #pragma unroll
      for (int r = 0; r < 16; ++r) {
        s0[r] = __builtin_amdgcn_exp2f(s0[r] - Mn);
        s1[r] = __builtin_amdgcn_exp2f(s1[r] - Mn);
      }
      float ls_[16];
      #pragma unroll
      for (int r = 0; r < 16; ++r) ls_[r] = s0[r] + s1[r];
      #pragma unroll
      for (int st = 8; st >= 1; st >>= 1)
        #pragma unroll
        for (int r = 0; r < 16; ++r) if (r < st) ls_[r] += ls_[r + st];
      float ls = ls_[0] + __shfl_xor(ls_[0], 32);
      L = L * sc + ls;
      // ---- P -> bf16 B-frags in-register (cvt_pk + permlane32_swap) ----
      bf16x8 pf0, pf1, pf2, pf3;
      build_pfrags(s0, pf0, pf1);
      build_pfrags(s1, pf2, pf3);
      // ---- rescale O ----
      #pragma unroll
      for (int r = 0; r < 16; ++r) { o0[r] *= sc; o1[r] *= sc; }
      // ---- O^T += V^T . P^T ----
      __builtin_amdgcn_s_setprio(1);
      #pragma unroll
      for (int ks = 0; ks < 4; ++ks) {
        int slot = 2 * ks + hf;
        bf16x8 v0 = *(const bf16x8*)&Vs[cur][lq * 64 + ((slot ^ swz) << 3)];
        bf16x8 v1 = *(const bf16x8*)&Vs[cur][(32 + lq) * 64 + ((slot ^ swz) << 3)];
        bf16x8 pf = (ks == 0) ? pf0 : (ks == 1) ? pf1 : (ks == 2) ? pf2 : pf3;
        o0 = __builtin_amdgcn_mfma_f32_32x32x16_bf16(v0, pf, o0, 0, 0, 0);
        o1 = __builtin_amdgcn_mfma_f32_32x32x16_bf16(v1, pf, o1, 0, 0, 0);
      }
      __builtin_amdgcn_s_setprio(0);
    }
    __syncthreads();
  }

  size_t rbB = ((size_t)b_ * Tt + qrow) * Dd + h * HDd;
  write_o(O, rbB, o0, o1, L, hf);
}

extern "C" void kernel_launch(void* const* d_in, const int* in_sizes, int n_in,
                              void* d_out, int out_size, void* d_ws, size_t ws_size,
                              hipStream_t stream) {
  const float* x    = (const float*)d_in[0];
  const float* Wqkv = (const float*)d_in[1];
  const float* bqkv = (const float*)d_in[2];
  const float* Wout = (const float*)d_in[3];
  const float* bout = (const float*)d_in[4];
  float* out = (float*)d_out;
  char* ws = (char*)d_ws;

  u16* xb    = (u16*)(ws + 0);           // 16,777,216
  u16* Wqkvt = (u16*)(ws + 16777216);    //  6,291,456
  u16* Woutt = (u16*)(ws + 23068672);    //  2,097,152
  u16* Qb    = (u16*)(ws + 25165824);    // 16,777,216
  u16* Kb    = (u16*)(ws + 41943040);    // 16,777,216
  u16* Vb    = (u16*)(ws + 58720256);    // 16,777,216
  u16* Vtb   = (u16*)(ws + 0);           // alias xb
  u16* Ob    = (u16*)(ws + 58720256);    // alias Vb

  cast_x_kernel<<<4096, 256, 0, stream>>>(x, xb, (MM * Dd) / 8);
  wcast_t_kernel<<<dim3(96, 32), 256, 0, stream>>>(Wqkv, Wqkvt, Dd, 3 * Dd);
  wcast_t_kernel<<<dim3(32, 32), 256, 0, stream>>>(Wout, Woutt, Dd, Dd);
  gemm_bt_kernel<0><<<dim3(24, 64), 256, 0, stream>>>(
      xb, Wqkvt, bqkv, nullptr, Qb, Kb, Vb, MM, 3 * Dd, Dd);
  vtrans_kernel<<<dim3(Tt / 32, HDd / 32, Bb * Hh), 256, 0, stream>>>(Vb, Vtb);
  attn_kernel<<<dim3(8, Bb * Hh), 256, 0, stream>>>(Qb, Kb, Vtb, Ob);
  gemm_bt_kernel<1><<<dim3(8, 64), 256, 0, stream>>>(
      Ob, Woutt, bout, out, nullptr, nullptr, nullptr, MM, Dd, Dd);
}

// Round 6
// 188.746 us; speedup vs baseline: 3.0452x; 1.0869x over previous
//
#include <hip/hip_runtime.h>

typedef unsigned short u16;
typedef __bf16 bf16x8 __attribute__((ext_vector_type(8)));
typedef float f32x4 __attribute__((ext_vector_type(4)));
typedef float f32x16 __attribute__((ext_vector_type(16)));

#define DEV __device__ __forceinline__

constexpr int Bb = 4, Tt = 2048, Dd = 1024, Hh = 16, HDd = 64;
constexpr int MM = Bb * Tt;        // 8192
constexpr float QSCALE = 0.125f * 1.4426950408889634f;  // 1/sqrt(64) * log2(e)

DEV u16 f2bf(float f) {
  unsigned u = __float_as_uint(f);
  u += 0x7fffu + ((u >> 16) & 1u);   // RNE
  return (u16)(u >> 16);
}

DEV unsigned cvtpk(float a, float b) {   // bf16(a) in lo16, bf16(b) in hi16
  unsigned r;
  asm("v_cvt_pk_bf16_f32 %0, %1, %2" : "=v"(r) : "v"(a), "v"(b));
  return r;
}

DEV void pswap(unsigned& a, unsigned& b) {  // half-exchange across lane-32 split
  // NOTE: callers must pass values that are NOT provably equal, else the
  // compiler may alias a,b into one VGPR and the swap degenerates (R4 NaN).
  asm("v_permlane32_swap_b32 %0, %1" : "+v"(a), "+v"(b));
}

DEV void gload_lds16(const u16* g, u16* l) {
  __builtin_amdgcn_global_load_lds(
      (const __attribute__((address_space(1))) void*)g,
      (__attribute__((address_space(3))) void*)l, 16, 0, 0);
}

// ---------------- cast x -> bf16 ----------------
__global__ __launch_bounds__(256) void cast_x_kernel(const float* __restrict__ in,
                                                     u16* __restrict__ out, int n8) {
  int i = blockIdx.x * 256 + threadIdx.x;
  if (i >= n8) return;
  const float4* p = (const float4*)in + (size_t)i * 2;
  float4 v0 = p[0], v1 = p[1];
  union { u16 u[8]; uint4 v; } t;
  t.u[0] = f2bf(v0.x); t.u[1] = f2bf(v0.y); t.u[2] = f2bf(v0.z); t.u[3] = f2bf(v0.w);
  t.u[4] = f2bf(v1.x); t.u[5] = f2bf(v1.y); t.u[6] = f2bf(v1.z); t.u[7] = f2bf(v1.w);
  ((uint4*)out)[i] = t.v;
}

// ---------- cast + transpose weights: [K][N] f32 -> [N][K] bf16 ----------
__global__ __launch_bounds__(256) void wcast_t_kernel(const float* __restrict__ in,
                                                      u16* __restrict__ out, int K, int N) {
  __shared__ float tile[32][33];
  int n0 = blockIdx.x * 32, k0 = blockIdx.y * 32;
  int tx = threadIdx.x & 31, ty = threadIdx.x >> 5;
  #pragma unroll
  for (int yy = ty; yy < 32; yy += 8)
    tile[yy][tx] = in[(size_t)(k0 + yy) * N + n0 + tx];
  __syncthreads();
  #pragma unroll
  for (int yy = ty; yy < 32; yy += 8)
    out[(size_t)(n0 + yy) * K + k0 + tx] = f2bf(tile[tx][yy]);
}

// ---------------- V [bh][t][d] -> Vt [bh][d][t] (bf16) ----------------
__global__ __launch_bounds__(256) void vtrans_kernel(const u16* __restrict__ V,
                                                     u16* __restrict__ Vt) {
  __shared__ u16 tile[32][33];
  size_t base = (size_t)blockIdx.z * Tt * HDd;
  int t0 = blockIdx.x * 32, d0 = blockIdx.y * 32;
  int tx = threadIdx.x & 31, ty = threadIdx.x >> 5;
  #pragma unroll
  for (int yy = ty; yy < 32; yy += 8)
    tile[yy][tx] = V[base + (size_t)(t0 + yy) * HDd + d0 + tx];
  __syncthreads();
  #pragma unroll
  for (int yy = ty; yy < 32; yy += 8)
    Vt[base + (size_t)(d0 + yy) * Tt + t0 + tx] = tile[tx][yy];
}

// ---------------- GEMM: A[M][K] bf16 * Bt[N][K] bf16 ----------------
DEV void stage_tile(const u16* __restrict__ src, int row0, int k0, int ld, u16* lds) {
  int t = threadIdx.x, w = t >> 6;
  #pragma unroll
  for (int j = 0; j < 2; ++j) {
    int e = (j * 256 + t) * 8;
    int r = e >> 5;
    int slot = (e >> 3) & 3;
    int c = (slot ^ ((r >> 1) & 3)) << 3;
    gload_lds16(src + (size_t)(row0 + r) * ld + k0 + c, lds + j * 2048 + w * 512);
  }
}

template <int EPI>   // 0: QKV coalesced epilogue, 1: plain f32 + bias
__global__ __launch_bounds__(256) void gemm_bt_kernel(
    const u16* __restrict__ A, const u16* __restrict__ Bt,
    const float* __restrict__ bias, float* __restrict__ Cf,
    u16* __restrict__ Qb, u16* __restrict__ Kb, u16* __restrict__ Vb,
    int M, int N, int Kd) {
  __shared__ __align__(16) u16 SH[16384];   // As[2] | Bs[2]; reused by epilogue
  // XCD-aware bijective swizzle: nwg % 8 == 0 for both launches.
  int nx = N >> 7;
  int bid = blockIdx.y * nx + blockIdx.x;
  int nwg = (M >> 7) * nx;
  int swz = (bid & 7) * (nwg >> 3) + (bid >> 3);
  int m0 = (swz / nx) * 128, n0 = (swz % nx) * 128;

  int tid = threadIdx.x, l = tid & 63, w = tid >> 6;
  int lo = l & 15, g = l >> 4;
  int wm = (w >> 1) * 64, wn = (w & 1) * 64;
  f32x4 acc[4][4] = {};
  stage_tile(A, m0, 0, Kd, SH);
  stage_tile(Bt, n0, 0, Kd, SH + 8192);
  __syncthreads();
  int nk = Kd >> 5;
  for (int kt = 0; kt < nk; ++kt) {
    int cur = kt & 1;
    if (kt + 1 < nk) {
      stage_tile(A, m0, (kt + 1) * 32, Kd, SH + (cur ^ 1) * 4096);
      stage_tile(Bt, n0, (kt + 1) * 32, Kd, SH + 8192 + (cur ^ 1) * 4096);
    }
    const u16* Ac = SH + cur * 4096;
    const u16* Bc = SH + 8192 + cur * 4096;
    bf16x8 a[4], b[4];
    #pragma unroll
    for (int i = 0; i < 4; ++i) {
      int row = wm + i * 16 + lo;
      a[i] = *(const bf16x8*)&Ac[row * 32 + ((g ^ ((row >> 1) & 3)) << 3)];
    }
    #pragma unroll
    for (int j = 0; j < 4; ++j) {
      int row = wn + j * 16 + lo;
      b[j] = *(const bf16x8*)&Bc[row * 32 + ((g ^ ((row >> 1) & 3)) << 3)];
    }
    #pragma unroll
    for (int i = 0; i < 4; ++i)
      #pragma unroll
      for (int j = 0; j < 4; ++j)
        acc[i][j] = __builtin_amdgcn_mfma_f32_16x16x32_bf16(a[i], b[j], acc[i][j], 0, 0, 0);
    __syncthreads();
  }
  if (EPI == 0) {
    // QKV epilogue: stage wave's 64x64 bf16 tile in LDS (XOR slot-swizzled),
    // then 8x {ds_read_b128 -> global_store_dwordx4}, 64 lanes = 1KB/instr.
    u16* ep = SH + w * 4096;
    int nblk = n0 + wn;
    int hh = nblk / 192, which = (nblk % 192) >> 6;
    float qs = (which == 0) ? QSCALE : 1.0f;
    #pragma unroll
    for (int j = 0; j < 4; ++j) {
      float bv = bias[nblk + j * 16 + lo];
      int slot = j * 2 + (lo >> 3);
      #pragma unroll
      for (int i = 0; i < 4; ++i) {
        #pragma unroll
        for (int r = 0; r < 4; ++r) {
          int lrow = i * 16 + g * 4 + r;
          ep[lrow * 64 + ((slot ^ (lrow & 7)) << 3) + (lo & 7)] =
              f2bf((acc[i][j][r] + bv) * qs);
        }
      }
    }
    asm volatile("s_waitcnt lgkmcnt(0)" ::: "memory");
    u16* dst = (which == 0) ? Qb : (which == 1) ? Kb : Vb;
    int mblk = m0 + wm;
    int b_ = mblk >> 11, t0 = mblk & (Tt - 1);
    dst += ((size_t)(b_ * Hh + hh) * Tt + t0) * HDd;
    #pragma unroll
    for (int s = 0; s < 8; ++s) {
      int row = s * 8 + (l >> 3);
      int phys = ((l & 7) ^ (row & 7)) << 3;
      uint4 v = *(const uint4*)&ep[row * 64 + phys];
      *(uint4*)(dst + row * 64 + (l & 7) * 8) = v;
    }
  } else {
    #pragma unroll
    for (int j = 0; j < 4; ++j) {
      int n = n0 + wn + j * 16 + lo;
      float bv = bias[n];
      #pragma unroll
      for (int i = 0; i < 4; ++i) {
        #pragma unroll
        for (int r = 0; r < 4; ++r) {
          int m = m0 + wm + i * 16 + g * 4 + r;
          Cf[(size_t)m * N + n] = acc[i][j][r] + bv;
        }
      }
    }
  }
}

// ---------------- flash attention (causal), paired q-blocks ----------------
// grid (8, B*H), 256 threads = 4 waves. Block p handles q-block JA=15-p then
// JB=p (128 rows each): ntA+ntB = 34 k-tiles for EVERY block -> balance.
// Softmax: R3's shfl_xor cross-half reduce + defer-max (T13, vote-guarded).
DEV void stage64x64(const u16* __restrict__ g, size_t rstride, u16* lds) {
  int t = threadIdx.x, w = t >> 6;
  #pragma unroll
  for (int j = 0; j < 2; ++j) {
    int e = j * 256 + t;
    int r = e >> 3, p = e & 7;
    int lg = p ^ (r & 7);
    gload_lds16(g + (size_t)r * rstride + lg * 8, lds + (size_t)(j * 256 + w * 64) * 8);
  }
}

DEV void build_pfrags(const f32x16& s, bf16x8& f0, bf16x8& f1) {
  unsigned w0 = cvtpk(s[0], s[1]),  w1 = cvtpk(s[2], s[3]);
  unsigned w2 = cvtpk(s[4], s[5]),  w3 = cvtpk(s[6], s[7]);
  unsigned w4 = cvtpk(s[8], s[9]),  w5 = cvtpk(s[10], s[11]);
  unsigned w6 = cvtpk(s[12], s[13]), w7 = cvtpk(s[14], s[15]);
  pswap(w0, w2);
  pswap(w1, w3);
  pswap(w4, w6);
  pswap(w5, w7);
  union { unsigned u[4]; bf16x8 v; } t0, t1;
  t0.u[0] = w0; t0.u[1] = w1; t0.u[2] = w2; t0.u[3] = w3;
  t1.u[0] = w4; t1.u[1] = w5; t1.u[2] = w6; t1.u[3] = w7;
  f0 = t0.v; f1 = t1.v;
}

DEV void write_o(u16* __restrict__ O, size_t rowbase, const f32x16& o0,
                 const f32x16& o1, float L, int hf) {
  float inv = 1.0f / L;
  #pragma unroll
  for (int m = 0; m < 4; ++m) {
    uint2 v0, v1;
    v0.x = cvtpk(o0[4 * m] * inv,     o0[4 * m + 1] * inv);
    v0.y = cvtpk(o0[4 * m + 2] * inv, o0[4 * m + 3] * inv);
    *(uint2*)(O + rowbase + m * 8 + hf * 4) = v0;
    v1.x = cvtpk(o1[4 * m] * inv,     o1[4 * m + 1] * inv);
    v1.y = cvtpk(o1[4 * m + 2] * inv, o1[4 * m + 3] * inv);
    *(uint2*)(O + rowbase + 32 + m * 8 + hf * 4) = v1;
  }
}

__global__ __launch_bounds__(256) void attn_kernel(const u16* __restrict__ Q,
                                                   const u16* __restrict__ K,
                                                   const u16* __restrict__ Vt,
                                                   u16* __restrict__ O) {
  __shared__ __align__(16) u16 Ks[2][4096];
  __shared__ __align__(16) u16 Vs[2][4096];
  int bh = blockIdx.y;
  int b_ = bh >> 4, h = bh & 15;
  const u16* Qp = Q + (size_t)bh * Tt * HDd;
  const u16* Kp = K + (size_t)bh * Tt * HDd;
  const u16* Vp = Vt + (size_t)bh * HDd * Tt;
  int tid = threadIdx.x, w = tid >> 6, l = tid & 63;
  int lq = l & 31, hf = l >> 5;
  int p = blockIdx.x;
  int JA = 15 - p, JB = p;
  int ntA = 2 * JA + 2, ntB = 2 * JB + 2, ntT = ntA + ntB;   // == 34

  int q0 = 128 * JA + 32 * w;
  int qrow = q0 + lq;

  bf16x8 aq[4];
  #pragma unroll
  for (int s = 0; s < 4; ++s)
    aq[s] = *(const bf16x8*)(Qp + (size_t)qrow * HDd + s * 16 + hf * 8);

  f32x16 o0 = {}, o1 = {};
  float M = -1e30f, L = 0.f;

  stage64x64(Kp, HDd, Ks[0]);
  stage64x64(Vp, Tt, Vs[0]);
  __syncthreads();

  for (int it = 0; it < ntT; ++it) {
    if (it == ntA) {
      size_t rbA = ((size_t)b_ * Tt + qrow) * Dd + h * HDd;
      write_o(O, rbA, o0, o1, L, hf);
      #pragma unroll
      for (int r = 0; r < 16; ++r) { o0[r] = 0.f; o1[r] = 0.f; }
      M = -1e30f; L = 0.f;
      q0 = 128 * JB + 32 * w;
      qrow = q0 + lq;
      #pragma unroll
      for (int s = 0; s < 4; ++s)
        aq[s] = *(const bf16x8*)(Qp + (size_t)qrow * HDd + s * 16 + hf * 8);
    }
    int kt = (it < ntA ? it : it - ntA) * 64;
    int cur = it & 1;
    if (it + 1 < ntT) {
      int nkt = (it + 1 < ntA ? it + 1 : it + 1 - ntA) * 64;
      stage64x64(Kp + (size_t)nkt * HDd, HDd, Ks[cur ^ 1]);
      stage64x64(Vp + nkt, Tt, Vs[cur ^ 1]);
    }
    if (kt < q0 + 32) {
      // ---- S^T = K . Q^T ----
      f32x16 s0 = {}, s1 = {};
      int swz = lq & 7;
      __builtin_amdgcn_s_setprio(1);
      #pragma unroll
      for (int ds = 0; ds < 4; ++ds) {
        int slot = 2 * ds + hf;
        bf16x8 k0 = *(const bf16x8*)&Ks[cur][lq * 64 + ((slot ^ swz) << 3)];
        bf16x8 k1 = *(const bf16x8*)&Ks[cur][(32 + lq) * 64 + ((slot ^ swz) << 3)];
        s0 = __builtin_amdgcn_mfma_f32_32x32x16_bf16(k0, aq[ds], s0, 0, 0, 0);
        s1 = __builtin_amdgcn_mfma_f32_32x32x16_bf16(k1, aq[ds], s1, 0, 0, 0);
      }
      __builtin_amdgcn_s_setprio(0);
      // ---- causal mask (diagonal-touching tiles only) ----
      if (kt + 63 > q0) {
        #pragma unroll
        for (int r = 0; r < 16; ++r) {
          int kg = kt + (r & 3) + 8 * (r >> 2) + 4 * hf;
          if (kg > qrow)      s0[r] = -INFINITY;
          if (kg + 32 > qrow) s1[r] = -INFINITY;
        }
      }
      // ---- online softmax: in-lane tree + one cross-half shuffle ----
      float mx_[16];
      #pragma unroll
      for (int r = 0; r < 16; ++r) mx_[r] = fmaxf(s0[r], s1[r]);
      #pragma unroll
      for (int st = 8; st >= 1; st >>= 1)
        #pragma unroll
        for (int r = 0; r < 16; ++r) if (r < st) mx_[r] = fmaxf(mx_[r], mx_[r + st]);
      float mx = fmaxf(mx_[0], __shfl_xor(mx_[0], 32));
      float sc = 1.f;
      if (!__all(mx <= M + 8.f)) {   // defer-max (T13): skip rescale on small growth
        float Mn = fmaxf(M, mx);
        sc = __builtin_amdgcn_exp2f(M - Mn);
        M = Mn;
        #pragma unroll
        for (int r = 0; r < 16; ++r) { o0[r] *= sc; o1[r] *= sc; }
      }
      #pragma unroll
      for (int r = 0; r < 16; ++r) {
        s0[r] = __builtin_amdgcn_exp2f(s0[r] - M);
        s1[r] = __builtin_amdgcn_exp2f(s1[r] - M);
      }
      float ls_[16];
      #pragma unroll
      for (int r = 0; r < 16; ++r) ls_[r] = s0[r] + s1[r];
      #pragma unroll
      for (int st = 8; st >= 1; st >>= 1)
        #pragma unroll
        for (int r = 0; r < 16; ++r) if (r < st) ls_[r] += ls_[r + st];
      float ls = ls_[0] + __shfl_xor(ls_[0], 32);
      L = L * sc + ls;
      // ---- P -> bf16 B-frags in-register (cvt_pk + permlane32_swap) ----
      bf16x8 pf0, pf1, pf2, pf3;
      build_pfrags(s0, pf0, pf1);
      build_pfrags(s1, pf2, pf3);
      // ---- O^T += V^T . P^T ----
      __builtin_amdgcn_s_setprio(1);
      #pragma unroll
      for (int ks = 0; ks < 4; ++ks) {
        int slot = 2 * ks + hf;
        bf16x8 v0 = *(const bf16x8*)&Vs[cur][lq * 64 + ((slot ^ swz) << 3)];
        bf16x8 v1 = *(const bf16x8*)&Vs[cur][(32 + lq) * 64 + ((slot ^ swz) << 3)];
        bf16x8 pf = (ks == 0) ? pf0 : (ks == 1) ? pf1 : (ks == 2) ? pf2 : pf3;
        o0 = __builtin_amdgcn_mfma_f32_32x32x16_bf16(v0, pf, o0, 0, 0, 0);
        o1 = __builtin_amdgcn_mfma_f32_32x32x16_bf16(v1, pf, o1, 0, 0, 0);
      }
      __builtin_amdgcn_s_setprio(0);
    }
    __syncthreads();
  }

  size_t rbB = ((size_t)b_ * Tt + qrow) * Dd + h * HDd;
  write_o(O, rbB, o0, o1, L, hf);
}

extern "C" void kernel_launch(void* const* d_in, const int* in_sizes, int n_in,
                              void* d_out, int out_size, void* d_ws, size_t ws_size,
                              hipStream_t stream) {
  const float* x    = (const float*)d_in[0];
  const float* Wqkv = (const float*)d_in[1];
  const float* bqkv = (const float*)d_in[2];
  const float* Wout = (const float*)d_in[3];
  const float* bout = (const float*)d_in[4];
  float* out = (float*)d_out;
  char* ws = (char*)d_ws;

  u16* xb    = (u16*)(ws + 0);           // 16,777,216
  u16* Wqkvt = (u16*)(ws + 16777216);    //  6,291,456
  u16* Woutt = (u16*)(ws + 23068672);    //  2,097,152
  u16* Qb    = (u16*)(ws + 25165824);    // 16,777,216
  u16* Kb    = (u16*)(ws + 41943040);    // 16,777,216
  u16* Vb    = (u16*)(ws + 58720256);    // 16,777,216
  u16* Vtb   = (u16*)(ws + 0);           // alias xb
  u16* Ob    = (u16*)(ws + 58720256);    // alias Vb

  cast_x_kernel<<<4096, 256, 0, stream>>>(x, xb, (MM * Dd) / 8);
  wcast_t_kernel<<<dim3(96, 32), 256, 0, stream>>>(Wqkv, Wqkvt, Dd, 3 * Dd);
  wcast_t_kernel<<<dim3(32, 32), 256, 0, stream>>>(Wout, Woutt, Dd, Dd);
  gemm_bt_kernel<0><<<dim3(24, 64), 256, 0, stream>>>(
      xb, Wqkvt, bqkv, nullptr, Qb, Kb, Vb, MM, 3 * Dd, Dd);
  vtrans_kernel<<<dim3(Tt / 32, HDd / 32, Bb * Hh), 256, 0, stream>>>(Vb, Vtb);
  attn_kernel<<<dim3(8, Bb * Hh), 256, 0, stream>>>(Qb, Kb, Vtb, Ob);
  gemm_bt_kernel<1><<<dim3(8, 64), 256, 0, stream>>>(
      Ob, Woutt, bout, out, nullptr, nullptr, nullptr, MM, Dd, Dd);
}

// Round 7
// 188.356 us; speedup vs baseline: 3.0516x; 1.0021x over previous
//
#include <hip/hip_runtime.h>

typedef unsigned short u16;
typedef __bf16 bf16x8 __attribute__((ext_vector_type(8)));
typedef float f32x4 __attribute__((ext_vector_type(4)));
typedef float f32x16 __attribute__((ext_vector_type(16)));

#define DEV __device__ __forceinline__

constexpr int Bb = 4, Tt = 2048, Dd = 1024, Hh = 16, HDd = 64;
constexpr int MM = Bb * Tt;        // 8192
constexpr float QSCALE = 0.125f * 1.4426950408889634f;  // 1/sqrt(64) * log2(e)

DEV u16 f2bf(float f) {
  unsigned u = __float_as_uint(f);
  u += 0x7fffu + ((u >> 16) & 1u);   // RNE
  return (u16)(u >> 16);
}

DEV unsigned cvtpk(float a, float b) {   // bf16(a) in lo16, bf16(b) in hi16
  unsigned r;
  asm("v_cvt_pk_bf16_f32 %0, %1, %2" : "=v"(r) : "v"(a), "v"(b));
  return r;
}

DEV void pswap(unsigned& a, unsigned& b) {  // half-exchange across lane-32 split
  // NOTE: callers must pass values that are NOT provably equal, else the
  // compiler may alias a,b into one VGPR and the swap degenerates (R4 NaN).
  asm("v_permlane32_swap_b32 %0, %1" : "+v"(a), "+v"(b));
}

DEV void gload_lds16(const u16* g, u16* l) {
  __builtin_amdgcn_global_load_lds(
      (const __attribute__((address_space(1))) void*)g,
      (__attribute__((address_space(3))) void*)l, 16, 0, 0);
}

// ---------------- cast x -> bf16 ----------------
__global__ __launch_bounds__(256) void cast_x_kernel(const float* __restrict__ in,
                                                     u16* __restrict__ out, int n8) {
  int i = blockIdx.x * 256 + threadIdx.x;
  if (i >= n8) return;
  const float4* p = (const float4*)in + (size_t)i * 2;
  float4 v0 = p[0], v1 = p[1];
  union { u16 u[8]; uint4 v; } t;
  t.u[0] = f2bf(v0.x); t.u[1] = f2bf(v0.y); t.u[2] = f2bf(v0.z); t.u[3] = f2bf(v0.w);
  t.u[4] = f2bf(v1.x); t.u[5] = f2bf(v1.y); t.u[6] = f2bf(v1.z); t.u[7] = f2bf(v1.w);
  ((uint4*)out)[i] = t.v;
}

// ---------- cast + transpose weights: [K][N] f32 -> [N][K] bf16 ----------
__global__ __launch_bounds__(256) void wcast_t_kernel(const float* __restrict__ in,
                                                      u16* __restrict__ out, int K, int N) {
  __shared__ float tile[32][33];
  int n0 = blockIdx.x * 32, k0 = blockIdx.y * 32;
  int tx = threadIdx.x & 31, ty = threadIdx.x >> 5;
  #pragma unroll
  for (int yy = ty; yy < 32; yy += 8)
    tile[yy][tx] = in[(size_t)(k0 + yy) * N + n0 + tx];
  __syncthreads();
  #pragma unroll
  for (int yy = ty; yy < 32; yy += 8)
    out[(size_t)(n0 + yy) * K + k0 + tx] = f2bf(tile[tx][yy]);
}

// ---------------- V [bh][t][d] -> Vt [bh][d][t] (bf16) ----------------
__global__ __launch_bounds__(256) void vtrans_kernel(const u16* __restrict__ V,
                                                     u16* __restrict__ Vt) {
  __shared__ u16 tile[32][33];
  size_t base = (size_t)blockIdx.z * Tt * HDd;
  int t0 = blockIdx.x * 32, d0 = blockIdx.y * 32;
  int tx = threadIdx.x & 31, ty = threadIdx.x >> 5;
  #pragma unroll
  for (int yy = ty; yy < 32; yy += 8)
    tile[yy][tx] = V[base + (size_t)(t0 + yy) * HDd + d0 + tx];
  __syncthreads();
  #pragma unroll
  for (int yy = ty; yy < 32; yy += 8)
    Vt[base + (size_t)(d0 + yy) * Tt + t0 + tx] = tile[tx][yy];
}

// ---------------- GEMM: A[M][K] bf16 * Bt[N][K] bf16 ----------------
DEV void stage_tile(const u16* __restrict__ src, int row0, int k0, int ld, u16* lds) {
  int t = threadIdx.x, w = t >> 6;
  #pragma unroll
  for (int j = 0; j < 2; ++j) {
    int e = (j * 256 + t) * 8;
    int r = e >> 5;
    int slot = (e >> 3) & 3;
    int c = (slot ^ ((r >> 1) & 3)) << 3;
    gload_lds16(src + (size_t)(row0 + r) * ld + k0 + c, lds + j * 2048 + w * 512);
  }
}

template <int EPI>   // 0: QKV coalesced epilogue, 1: plain f32 + bias
__global__ __launch_bounds__(256) void gemm_bt_kernel(
    const u16* __restrict__ A, const u16* __restrict__ Bt,
    const float* __restrict__ bias, float* __restrict__ Cf,
    u16* __restrict__ Qb, u16* __restrict__ Kb, u16* __restrict__ Vb,
    int M, int N, int Kd) {
  __shared__ __align__(16) u16 SH[16384];   // As[2] | Bs[2]; reused by epilogue
  // XCD-aware bijective swizzle: nwg % 8 == 0 for both launches.
  int nx = N >> 7;
  int bid = blockIdx.y * nx + blockIdx.x;
  int nwg = (M >> 7) * nx;
  int swz = (bid & 7) * (nwg >> 3) + (bid >> 3);
  int m0 = (swz / nx) * 128, n0 = (swz % nx) * 128;

  int tid = threadIdx.x, l = tid & 63, w = tid >> 6;
  int lo = l & 15, g = l >> 4;
  int wm = (w >> 1) * 64, wn = (w & 1) * 64;
  f32x4 acc[4][4] = {};
  stage_tile(A, m0, 0, Kd, SH);
  stage_tile(Bt, n0, 0, Kd, SH + 8192);
  __syncthreads();
  int nk = Kd >> 5;
  for (int kt = 0; kt < nk; ++kt) {
    int cur = kt & 1;
    if (kt + 1 < nk) {
      stage_tile(A, m0, (kt + 1) * 32, Kd, SH + (cur ^ 1) * 4096);
      stage_tile(Bt, n0, (kt + 1) * 32, Kd, SH + 8192 + (cur ^ 1) * 4096);
    }
    const u16* Ac = SH + cur * 4096;
    const u16* Bc = SH + 8192 + cur * 4096;
    bf16x8 a[4], b[4];
    #pragma unroll
    for (int i = 0; i < 4; ++i) {
      int row = wm + i * 16 + lo;
      a[i] = *(const bf16x8*)&Ac[row * 32 + ((g ^ ((row >> 1) & 3)) << 3)];
    }
    #pragma unroll
    for (int j = 0; j < 4; ++j) {
      int row = wn + j * 16 + lo;
      b[j] = *(const bf16x8*)&Bc[row * 32 + ((g ^ ((row >> 1) & 3)) << 3)];
    }
    #pragma unroll
    for (int i = 0; i < 4; ++i)
      #pragma unroll
      for (int j = 0; j < 4; ++j)
        acc[i][j] = __builtin_amdgcn_mfma_f32_16x16x32_bf16(a[i], b[j], acc[i][j], 0, 0, 0);
    __syncthreads();
  }
  if (EPI == 0) {
    // QKV epilogue: stage wave's 64x64 bf16 tile in LDS (XOR slot-swizzled),
    // then 8x {ds_read_b128 -> global_store_dwordx4}, 64 lanes = 1KB/instr.
    u16* ep = SH + w * 4096;
    int nblk = n0 + wn;
    int hh = nblk / 192, which = (nblk % 192) >> 6;
    float qs = (which == 0) ? QSCALE : 1.0f;
    #pragma unroll
    for (int j = 0; j < 4; ++j) {
      float bv = bias[nblk + j * 16 + lo];
      int slot = j * 2 + (lo >> 3);
      #pragma unroll
      for (int i = 0; i < 4; ++i) {
        #pragma unroll
        for (int r = 0; r < 4; ++r) {
          int lrow = i * 16 + g * 4 + r;
          ep[lrow * 64 + ((slot ^ (lrow & 7)) << 3) + (lo & 7)] =
              f2bf((acc[i][j][r] + bv) * qs);
        }
      }
    }
    asm volatile("s_waitcnt lgkmcnt(0)" ::: "memory");
    u16* dst = (which == 0) ? Qb : (which == 1) ? Kb : Vb;
    int mblk = m0 + wm;
    int b_ = mblk >> 11, t0 = mblk & (Tt - 1);
    dst += ((size_t)(b_ * Hh + hh) * Tt + t0) * HDd;
    #pragma unroll
    for (int s = 0; s < 8; ++s) {
      int row = s * 8 + (l >> 3);
      int phys = ((l & 7) ^ (row & 7)) << 3;
      uint4 v = *(const uint4*)&ep[row * 64 + phys];
      *(uint4*)(dst + row * 64 + (l & 7) * 8) = v;
    }
  } else {
    #pragma unroll
    for (int j = 0; j < 4; ++j) {
      int n = n0 + wn + j * 16 + lo;
      float bv = bias[n];
      #pragma unroll
      for (int i = 0; i < 4; ++i) {
        #pragma unroll
        for (int r = 0; r < 4; ++r) {
          int m = m0 + wm + i * 16 + g * 4 + r;
          Cf[(size_t)m * N + n] = acc[i][j][r] + bv;
        }
      }
    }
  }
}

// ---------------- flash attention (causal), paired q-blocks ----------------
// grid (8, 64) reinterpreted so id%8 == bh%8: all 8 paired-blocks of one bh
// land on ONE XCD (K/V working set 8 bh x 512KB = 4MB = one L2).
// Triple-buffered K/V stage with counted vmcnt (T3/T4): stage(it+2) each
// iter, s_waitcnt vmcnt(4) + raw s_barrier -- prefetch survives the barrier.
DEV void stage64x64(const u16* __restrict__ g, size_t rstride, u16* lds) {
  int t = threadIdx.x, w = t >> 6;
  #pragma unroll
  for (int j = 0; j < 2; ++j) {
    int e = j * 256 + t;
    int r = e >> 3, p = e & 7;
    int lg = p ^ (r & 7);
    gload_lds16(g + (size_t)r * rstride + lg * 8, lds + (size_t)(j * 256 + w * 64) * 8);
  }
}

DEV void build_pfrags(const f32x16& s, bf16x8& f0, bf16x8& f1) {
  unsigned w0 = cvtpk(s[0], s[1]),  w1 = cvtpk(s[2], s[3]);
  unsigned w2 = cvtpk(s[4], s[5]),  w3 = cvtpk(s[6], s[7]);
  unsigned w4 = cvtpk(s[8], s[9]),  w5 = cvtpk(s[10], s[11]);
  unsigned w6 = cvtpk(s[12], s[13]), w7 = cvtpk(s[14], s[15]);
  pswap(w0, w2);
  pswap(w1, w3);
  pswap(w4, w6);
  pswap(w5, w7);
  union { unsigned u[4]; bf16x8 v; } t0, t1;
  t0.u[0] = w0; t0.u[1] = w1; t0.u[2] = w2; t0.u[3] = w3;
  t1.u[0] = w4; t1.u[1] = w5; t1.u[2] = w6; t1.u[3] = w7;
  f0 = t0.v; f1 = t1.v;
}

DEV void write_o(u16* __restrict__ O, size_t rowbase, const f32x16& o0,
                 const f32x16& o1, float L, int hf) {
  float inv = 1.0f / L;
  #pragma unroll
  for (int m = 0; m < 4; ++m) {
    uint2 v0, v1;
    v0.x = cvtpk(o0[4 * m] * inv,     o0[4 * m + 1] * inv);
    v0.y = cvtpk(o0[4 * m + 2] * inv, o0[4 * m + 3] * inv);
    *(uint2*)(O + rowbase + m * 8 + hf * 4) = v0;
    v1.x = cvtpk(o1[4 * m] * inv,     o1[4 * m + 1] * inv);
    v1.y = cvtpk(o1[4 * m + 2] * inv, o1[4 * m + 3] * inv);
    *(uint2*)(O + rowbase + 32 + m * 8 + hf * 4) = v1;
  }
}

__global__ __launch_bounds__(256) void attn_kernel(const u16* __restrict__ Q,
                                                   const u16* __restrict__ K,
                                                   const u16* __restrict__ Vt,
                                                   u16* __restrict__ O) {
  __shared__ __align__(16) u16 Ks[3][4096];
  __shared__ __align__(16) u16 Vs[3][4096];
  // XCD-locality remap: linear id % 8 == blockIdx.x == bh % 8.
  int p = blockIdx.y & 7;
  int bh = ((int)blockIdx.y >> 3) * 8 + (int)blockIdx.x;
  int b_ = bh >> 4, h = bh & 15;
  const u16* Qp = Q + (size_t)bh * Tt * HDd;
  const u16* Kp = K + (size_t)bh * Tt * HDd;
  const u16* Vp = Vt + (size_t)bh * HDd * Tt;
  int tid = threadIdx.x, w = tid >> 6, l = tid & 63;
  int lq = l & 31, hf = l >> 5;
  int JA = 15 - p, JB = p;
  int ntA = 2 * JA + 2, ntB = 2 * JB + 2, ntT = ntA + ntB;   // == 34

  int q0 = 128 * JA + 32 * w;
  int qrow = q0 + lq;

  bf16x8 aq[4];
  #pragma unroll
  for (int s = 0; s < 4; ++s)
    aq[s] = *(const bf16x8*)(Qp + (size_t)qrow * HDd + s * 16 + hf * 8);

  f32x16 o0 = {}, o1 = {};
  float M = -1e30f, L = 0.f;

  // prologue: stage tiles 0 and 1 (4 loads/thread each), wait tile0 only.
  stage64x64(Kp, HDd, Ks[0]);
  stage64x64(Vp, Tt, Vs[0]);
  stage64x64(Kp + (size_t)64 * HDd, HDd, Ks[1]);
  stage64x64(Vp + 64, Tt, Vs[1]);
  asm volatile("s_waitcnt vmcnt(4)" ::: "memory");
  __builtin_amdgcn_s_barrier();

  for (int it = 0; it < ntT; ++it) {
    if (it == ntA) {
      // finalize pass A, switch to pass B (register-only + stores; no sync)
      size_t rbA = ((size_t)b_ * Tt + qrow) * Dd + h * HDd;
      write_o(O, rbA, o0, o1, L, hf);
      #pragma unroll
      for (int r = 0; r < 16; ++r) { o0[r] = 0.f; o1[r] = 0.f; }
      M = -1e30f; L = 0.f;
      q0 = 128 * JB + 32 * w;
      qrow = q0 + lq;
      #pragma unroll
      for (int s = 0; s < 4; ++s)
        aq[s] = *(const bf16x8*)(Qp + (size_t)qrow * HDd + s * 16 + hf * 8);
    }
    // stage tile it+2 into buf[(it+2)%3] (that buffer was consumed at it-1;
    // the barrier ending it-1 makes the overwrite safe)
    if (it + 2 < ntT) {
      int t2 = it + 2;
      int nkt = (t2 < ntA ? t2 : t2 - ntA) * 64;
      int bi = t2 % 3;
      stage64x64(Kp + (size_t)nkt * HDd, HDd, Ks[bi]);
      stage64x64(Vp + nkt, Tt, Vs[bi]);
    }
    int kt = (it < ntA ? it : it - ntA) * 64;
    const u16* Kc = Ks[it % 3];
    const u16* Vc = Vs[it % 3];
    if (kt < q0 + 32) {
      // ---- S^T = K . Q^T ----
      f32x16 s0 = {}, s1 = {};
      int swz = lq & 7;
      __builtin_amdgcn_s_setprio(1);
      #pragma unroll
      for (int ds = 0; ds < 4; ++ds) {
        int slot = 2 * ds + hf;
        bf16x8 k0 = *(const bf16x8*)&Kc[lq * 64 + ((slot ^ swz) << 3)];
        bf16x8 k1 = *(const bf16x8*)&Kc[(32 + lq) * 64 + ((slot ^ swz) << 3)];
        s0 = __builtin_amdgcn_mfma_f32_32x32x16_bf16(k0, aq[ds], s0, 0, 0, 0);
        s1 = __builtin_amdgcn_mfma_f32_32x32x16_bf16(k1, aq[ds], s1, 0, 0, 0);
      }
      __builtin_amdgcn_s_setprio(0);
      // ---- causal mask (diagonal-touching tiles only) ----
      if (kt + 63 > q0) {
        #pragma unroll
        for (int r = 0; r < 16; ++r) {
          int kg = kt + (r & 3) + 8 * (r >> 2) + 4 * hf;
          if (kg > qrow)      s0[r] = -INFINITY;
          if (kg + 32 > qrow) s1[r] = -INFINITY;
        }
      }
      // ---- online softmax: in-lane tree + one cross-half shuffle ----
      float mx_[16];
      #pragma unroll
      for (int r = 0; r < 16; ++r) mx_[r] = fmaxf(s0[r], s1[r]);
      #pragma unroll
      for (int st = 8; st >= 1; st >>= 1)
        #pragma unroll
        for (int r = 0; r < 16; ++r) if (r < st) mx_[r] = fmaxf(mx_[r], mx_[r + st]);
      float mx = fmaxf(mx_[0], __shfl_xor(mx_[0], 32));
      float sc = 1.f;
      if (!__all(mx <= M + 8.f)) {   // defer-max (T13): skip rescale on small growth
        float Mn = fmaxf(M, mx);
        sc = __builtin_amdgcn_exp2f(M - Mn);
        M = Mn;
        #pragma unroll
        for (int r = 0; r < 16; ++r) { o0[r] *= sc; o1[r] *= sc; }
      }
      #pragma unroll
      for (int r = 0; r < 16; ++r) {
        s0[r] = __builtin_amdgcn_exp2f(s0[r] - M);
        s1[r] = __builtin_amdgcn_exp2f(s1[r] - M);
      }
      float ls_[16];
      #pragma unroll
      for (int r = 0; r < 16; ++r) ls_[r] = s0[r] + s1[r];
      #pragma unroll
      for (int st = 8; st >= 1; st >>= 1)
        #pragma unroll
        for (int r = 0; r < 16; ++r) if (r < st) ls_[r] += ls_[r + st];
      float ls = ls_[0] + __shfl_xor(ls_[0], 32);
      L = L * sc + ls;
      // ---- P -> bf16 B-frags in-register (cvt_pk + permlane32_swap) ----
      bf16x8 pf0, pf1, pf2, pf3;
      build_pfrags(s0, pf0, pf1);
      build_pfrags(s1, pf2, pf3);
      // ---- O^T += V^T . P^T ----
      __builtin_amdgcn_s_setprio(1);
      #pragma unroll
      for (int ks = 0; ks < 4; ++ks) {
        int slot = 2 * ks + hf;
        bf16x8 v0 = *(const bf16x8*)&Vc[lq * 64 + ((slot ^ swz) << 3)];
        bf16x8 v1 = *(const bf16x8*)&Vc[(32 + lq) * 64 + ((slot ^ swz) << 3)];
        bf16x8 pf = (ks == 0) ? pf0 : (ks == 1) ? pf1 : (ks == 2) ? pf2 : pf3;
        o0 = __builtin_amdgcn_mfma_f32_32x32x16_bf16(v0, pf, o0, 0, 0, 0);
        o1 = __builtin_amdgcn_mfma_f32_32x32x16_bf16(v1, pf, o1, 0, 0, 0);
      }
      __builtin_amdgcn_s_setprio(0);
    }
    // end-of-tile: ensure tile it+1 is resident; keep it+2's loads in flight.
    if (it + 2 < ntT) {
      asm volatile("s_waitcnt vmcnt(4)" ::: "memory");
    } else {
      asm volatile("s_waitcnt vmcnt(0)" ::: "memory");
    }
    __builtin_amdgcn_s_barrier();
  }

  size_t rbB = ((size_t)b_ * Tt + qrow) * Dd + h * HDd;
  write_o(O, rbB, o0, o1, L, hf);
}

extern "C" void kernel_launch(void* const* d_in, const int* in_sizes, int n_in,
                              void* d_out, int out_size, void* d_ws, size_t ws_size,
                              hipStream_t stream) {
  const float* x    = (const float*)d_in[0];
  const float* Wqkv = (const float*)d_in[1];
  const float* bqkv = (const float*)d_in[2];
  const float* Wout = (const float*)d_in[3];
  const float* bout = (const float*)d_in[4];
  float* out = (float*)d_out;
  char* ws = (char*)d_ws;

  u16* xb    = (u16*)(ws + 0);           // 16,777,216
  u16* Wqkvt = (u16*)(ws + 16777216);    //  6,291,456
  u16* Woutt = (u16*)(ws + 23068672);    //  2,097,152
  u16* Qb    = (u16*)(ws + 25165824);    // 16,777,216
  u16* Kb    = (u16*)(ws + 41943040);    // 16,777,216
  u16* Vb    = (u16*)(ws + 58720256);    // 16,777,216
  u16* Vtb   = (u16*)(ws + 0);           // alias xb
  u16* Ob    = (u16*)(ws + 58720256);    // alias Vb

  cast_x_kernel<<<4096, 256, 0, stream>>>(x, xb, (MM * Dd) / 8);
  wcast_t_kernel<<<dim3(96, 32), 256, 0, stream>>>(Wqkv, Wqkvt, Dd, 3 * Dd);
  wcast_t_kernel<<<dim3(32, 32), 256, 0, stream>>>(Wout, Woutt, Dd, Dd);
  gemm_bt_kernel<0><<<dim3(24, 64), 256, 0, stream>>>(
      xb, Wqkvt, bqkv, nullptr, Qb, Kb, Vb, MM, 3 * Dd, Dd);
  vtrans_kernel<<<dim3(Tt / 32, HDd / 32, Bb * Hh), 256, 0, stream>>>(Vb, Vtb);
  attn_kernel<<<dim3(8, 64), 256, 0, stream>>>(Qb, Kb, Vtb, Ob);
  gemm_bt_kernel<1><<<dim3(8, 64), 256, 0, stream>>>(
      Ob, Woutt, bout, out, nullptr, nullptr, nullptr, MM, Dd, Dd);
}